// Round 11
// baseline (103.718 us; speedup 1.0000x reference)
//
#include <hip/hip_runtime.h>
#include <hip/hip_bf16.h>

#define Bn 8
#define Cn 128
#define Hn 64
#define Wn 64
#define HWn 4096
#define KK 9

typedef short short8 __attribute__((ext_vector_type(8)));
typedef float f32x4 __attribute__((ext_vector_type(4)));

__device__ inline unsigned short f2b(float v) {
    __hip_bfloat16 h = __float2bfloat16(v);
    return *reinterpret_cast<unsigned short*>(&h);
}
__device__ inline float b2f(unsigned short u) {
    return __uint_as_float(((unsigned int)u) << 16);
}

// ---------------------------------------------------------------------------
// K1: per-(b,c) plane streaming sums (stride 10):
//  [0]=sum(X2) [1]=row0 [2]=row63 [3]=col0 [4]=col63 [5]=sum(Y2)
//  [6]=x00 [7]=x063 [8]=x630 [9]=x6363
// ---------------------------------------------------------------------------
__global__ __launch_bounds__(256) void k_pre(
    const float* __restrict__ X2, const float* __restrict__ Y2,
    float* __restrict__ pws)
{
    int bc = blockIdx.x, t = threadIdx.x;
    const float4* xp = (const float4*)(X2 + (size_t)bc * HWn);
    const float4* yp = (const float4*)(Y2 + (size_t)bc * HWn);
    float v[10];
#pragma unroll
    for (int k = 0; k < 10; k++) v[k] = 0.f;
#pragma unroll
    for (int i = 0; i < 4; i++) {
        int q = t + i * 256;
        float4 x = xp[q], y = yp[q];
        float s4 = x.x + x.y + x.z + x.w;
        v[0] += s4;
        v[5] += y.x + y.y + y.z + y.w;
        int px = q * 4, h = px >> 6, w4 = px & 63;
        if (h == 0)   v[1] += s4;
        if (h == 63)  v[2] += s4;
        if (w4 == 0)  v[3] += x.x;
        if (w4 == 60) v[4] += x.w;
        if (px == 0)    v[6] += x.x;
        if (px == 60)   v[7] += x.w;
        if (px == 4032) v[8] += x.x;
        if (px == 4092) v[9] += x.w;
    }
#pragma unroll
    for (int k = 0; k < 10; k++)
#pragma unroll
        for (int off = 32; off; off >>= 1)
            v[k] += __shfl_down(v[k], off);
    __shared__ float red[4][10];
    int lane = t & 63, wv = t >> 6;
    if (lane == 0) {
#pragma unroll
        for (int k = 0; k < 10; k++) red[wv][k] = v[k];
    }
    __syncthreads();
    if (t < 10) pws[bc * 10 + t] = red[0][t] + red[1][t] + red[2][t] + red[3][t];
}

// ---------------------------------------------------------------------------
// K2: 32 blocks (4 per batch). Closed-form means -> MLP -> cf (LDS only) ->
// build combined GEMM weights:
//   C[b][t][o][c] = wf_x[o,c]*sw[c,t] + wf_d[o,c]*cf[b,c,t]   (bf16)
//   D[t][s][c]    = ws_x[s,c]*sw[c,t]  (s<9; rows 9..15 zero)  (bf16, blk 0)
// Also converts wf, ws to bf16 (wfb, wsb).
// ---------------------------------------------------------------------------
__global__ __launch_bounds__(256) void k_ctx(
    const float* __restrict__ pws, const float* __restrict__ sw,
    const float* __restrict__ w1, const float* __restrict__ w2,
    const float* __restrict__ w3, const float* __restrict__ wf,
    const float* __restrict__ wsp,
    unsigned short* __restrict__ wfb, unsigned short* __restrict__ wsb,
    unsigned short* __restrict__ Cb, unsigned short* __restrict__ Db)
{
    int blk = blockIdx.x, b = blk >> 2, qd = blk & 3;
    int t = threadIdx.x;
    // weight conversion slices
    for (int i = t; i < 1024; i += 256) {
        int j = blk * 1024 + i;
        wfb[j] = f2b(wf[j]);
    }
    if (t < 128) {
        int j = blk * 128 + t;
        int tt = j >> 8, c = j & 255;
        wsb[j] = (tt < KK) ? f2b(wsp[tt * 256 + c]) : (unsigned short)0;
    }

    __shared__ float mfc[256], c1[64], c2[64];
    __shared__ float scf[Cn][KK];
    __shared__ float ssw[Cn][KK];
    for (int j = t; j < Cn * KK; j += 256) ssw[j / 9][j % 9] = sw[j];

    if (t < 128) {
        const float* S = pws + (b * Cn + t) * 10;
        float T = S[0];
        float R[3]  = { S[2], 0.f, S[1] };
        float Cc[3] = { S[4], 0.f, S[3] };
        float Xc[3][3] = {{S[9], 0.f, S[8]}, {0.f, 0.f, 0.f}, {S[7], 0.f, S[6]}};
        float a = 0.f;
#pragma unroll
        for (int i = 0; i < 3; i++)
#pragma unroll
            for (int j = 0; j < 3; j++)
                a += sw[t * 9 + i * 3 + j] * (T - R[i] - Cc[j] + Xc[i][j]);
        mfc[t] = a * (1.f / HWn);
    } else {
        mfc[t] = pws[(b * Cn + (t - 128)) * 10 + 5] * (1.f / HWn);
    }
    __syncthreads();
    if (t < 64) {
        const float4* wr = (const float4*)(w1 + t * 256);
        float a = 0.f;
        for (int c = 0; c < 64; c++) {
            float4 v = wr[c];
            a += v.x * mfc[c*4] + v.y * mfc[c*4+1] + v.z * mfc[c*4+2] + v.w * mfc[c*4+3];
        }
        c1[t] = a;
    }
    __syncthreads();
    if (t < 64) {
        const float4* wr = (const float4*)(w2 + t * 64);
        float a = 0.f;
        for (int c = 0; c < 16; c++) {
            float4 v = wr[c];
            a += v.x * c1[c*4] + v.y * c1[c*4+1] + v.z * c1[c*4+2] + v.w * c1[c*4+3];
        }
        c2[t] = fmaxf(a, 0.f);
    }
    __syncthreads();
    // full cf for this batch into LDS (each of the 4 blocks per b redundantly)
    for (int j = t; j < Cn * KK; j += 256) {
        const float4* wr = (const float4*)(w3 + j * 64);
        float a = 0.f;
        for (int c = 0; c < 16; c++) {
            float4 v = wr[c];
            a += v.x * c2[c*4] + v.y * c2[c*4+1] + v.z * c2[c*4+2] + v.w * c2[c*4+3];
        }
        scf[j / 9][j % 9] = a;
    }
    __syncthreads();

    // C quarter: thread -> (o = qd*32 + t>>3, c16 = (t&7)*16)
    {
        int o = qd * 32 + (t >> 3);
        int cb = (t & 7) * 16;
        float wx[16], wd[16];
#pragma unroll
        for (int j = 0; j < 16; j++) {
            wx[j] = wf[o * 256 + cb + j];
            wd[j] = wf[o * 256 + 128 + cb + j];
        }
#pragma unroll
        for (int tt = 0; tt < 9; tt++) {
            unsigned short tmp[16];
#pragma unroll
            for (int j = 0; j < 16; j++) {
                int c = cb + j;
                tmp[j] = f2b(wx[j] * ssw[c][tt] + wd[j] * scf[c][tt]);
            }
            unsigned short* dst = Cb + (((size_t)b * 9 + tt) * Cn + o) * Cn + cb;
            *(uint4*)(dst)     = ((uint4*)tmp)[0];
            *(uint4*)(dst + 8) = ((uint4*)tmp)[1];
        }
    }
    // D (batch-independent): block 0 only
    if (blk == 0 && t < 128) {
        int s = t >> 3, cb = (t & 7) * 16;
#pragma unroll
        for (int tt = 0; tt < 9; tt++) {
            unsigned short tmp[16];
#pragma unroll
            for (int j = 0; j < 16; j++) {
                int c = cb + j;
                float v = (s < KK) ? wsp[s * 256 + c] * ssw[c][tt] : 0.f;
                tmp[j] = f2b(v);
            }
            unsigned short* dst = Db + ((size_t)tt * 16 + s) * Cn + cb;
            *(uint4*)(dst)     = ((uint4*)tmp)[0];
            *(uint4*)(dst + 8) = ((uint4*)tmp)[1];
        }
    }
}

// ---------------------------------------------------------------------------
// K3: THE GEMM. One block per (b,h) row, 512 threads, 67 KB LDS (2 blk/CU).
// Stage X2 halo tile [3 rows][66 wpos][128 ch] bf16 (swizzled) + Y2 row.
// Waves 0-3: T[o 0..127] = sum_t C_t @ X2shift_t            -> Tb bf16
// Waves 4-7: U = wf_d @ X2 (center)                         -> U bf16
//            sf = sum_t D_t @ X2shift_t + ws_y @ Y2          -> sfB f32
// ---------------------------------------------------------------------------
__global__ __launch_bounds__(512, 2) void k_main(
    const float* __restrict__ X2, const float* __restrict__ Y2,
    const unsigned short* __restrict__ Cb, const unsigned short* __restrict__ Db,
    const unsigned short* __restrict__ wfb, const unsigned short* __restrict__ wsb,
    unsigned short* __restrict__ Tb, unsigned short* __restrict__ U,
    float* __restrict__ sfB)
{
    __shared__ unsigned short sB[3][66][Cn];   // 50.7 KB, col swizzled
    __shared__ unsigned short sY[Wn][Cn];      // 16 KB

    int bid = blockIdx.x, b = bid & 7, h = bid >> 3;
    int t = threadIdx.x;

    // zero halo edge columns (wpos 0 and 65)
    for (int idx = t; idx < 768; idx += 512) {
        int r = idx / 256, side = (idx >> 7) & 1, c = idx & 127;
        sB[r][side ? 65 : 0][c] = 0;
    }
    // main X2 stage: unit = (c*3 + r)*16 + w4 ; 16-lane groups cover a row
    for (int u = t; u < 6144; u += 512) {
        int w4 = u & 15, rc = u >> 4;
        int r = rc % 3, c = rc / 3;
        int hh = h - 1 + r;
        float4 v = (hh >= 0 && hh < Hn)
            ? *(const float4*)(X2 + ((size_t)(b * Cn + c) * HWn + hh * Wn + w4 * 4))
            : (float4){0.f, 0.f, 0.f, 0.f};
        float va[4] = { v.x, v.y, v.z, v.w };
#pragma unroll
        for (int j = 0; j < 4; j++) {
            int wpos = w4 * 4 + j + 1;
            sB[r][wpos][c ^ (((wpos >> 1) & 7) << 3)] = f2b(va[j]);
        }
    }
    // Y2 stage
    for (int u = t; u < 2048; u += 512) {
        int w4 = u & 15, c = u >> 4;
        float4 v = *(const float4*)(Y2 + ((size_t)(b * Cn + c) * HWn + h * Wn + w4 * 4));
        float va[4] = { v.x, v.y, v.z, v.w };
#pragma unroll
        for (int j = 0; j < 4; j++) {
            int w = w4 * 4 + j;
            sY[w][c ^ (((w >> 1) & 7) << 3)] = f2b(va[j]);
        }
    }
    __syncthreads();

    int lane = t & 63, wv = t >> 6;
    int l16 = lane & 15, half = lane >> 4, kk = half * 8;

    if (wv < 4) {
        // ---- T: 32 output rows per wave, all 64 px
        int o0 = wv * 32;
        const unsigned short* Cbase = Cb + (size_t)b * 9 * Cn * Cn;
        f32x4 acc[2][4];
#pragma unroll
        for (int m = 0; m < 2; m++)
#pragma unroll
            for (int n = 0; n < 4; n++)
                acc[m][n] = (f32x4){0.f, 0.f, 0.f, 0.f};
#pragma unroll
        for (int tap = 0; tap < 9; tap++) {
            const int dh = tap / 3, dw = tap % 3;
#pragma unroll
            for (int ks = 0; ks < 4; ks++) {
                short8 av0 = *(const short8*)(Cbase + ((size_t)tap * Cn + o0 + l16) * Cn + ks * 32 + kk);
                short8 av1 = *(const short8*)(Cbase + ((size_t)tap * Cn + o0 + 16 + l16) * Cn + ks * 32 + kk);
#pragma unroll
                for (int n = 0; n < 4; n++) {
                    int wpos = n * 16 + l16 + dw;
                    int col = (ks * 32 + kk) ^ (((wpos >> 1) & 7) << 3);
                    short8 bv = *(const short8*)(&sB[dh][wpos][col]);
                    acc[0][n] = __builtin_amdgcn_mfma_f32_16x16x32_bf16(av0, bv, acc[0][n], 0, 0, 0);
                    acc[1][n] = __builtin_amdgcn_mfma_f32_16x16x32_bf16(av1, bv, acc[1][n], 0, 0, 0);
                }
            }
        }
#pragma unroll
        for (int m = 0; m < 2; m++)
#pragma unroll
            for (int n = 0; n < 4; n++)
#pragma unroll
                for (int r = 0; r < 4; r++) {
                    int o = o0 + m * 16 + half * 4 + r;
                    Tb[(size_t)(b * Cn + o) * HWn + h * Wn + n * 16 + l16] = f2b(acc[m][n][r]);
                }
    } else {
        // ---- U + sf for n-tile (wv-4)
        int n = wv - 4;
        int px = n * 16 + l16;
        // U: center tap, all 128 output rows
        f32x4 accu[8];
#pragma unroll
        for (int m = 0; m < 8; m++) accu[m] = (f32x4){0.f, 0.f, 0.f, 0.f};
        {
            int wpos = px + 1;
#pragma unroll
            for (int ks = 0; ks < 4; ks++) {
                int col = (ks * 32 + kk) ^ (((wpos >> 1) & 7) << 3);
                short8 bv = *(const short8*)(&sB[1][wpos][col]);
#pragma unroll
                for (int m = 0; m < 8; m++) {
                    short8 av = *(const short8*)(wfb + (m * 16 + l16) * 256 + 128 + ks * 32 + kk);
                    accu[m] = __builtin_amdgcn_mfma_f32_16x16x32_bf16(av, bv, accu[m], 0, 0, 0);
                }
            }
        }
#pragma unroll
        for (int m = 0; m < 8; m++)
#pragma unroll
            for (int r = 0; r < 4; r++) {
                int o = m * 16 + half * 4 + r;
                U[(size_t)(b * Cn + o) * HWn + h * Wn + px] = f2b(accu[m][r]);
            }
        // sf: 9 shifted taps (D) + Y2 term (ws_y)
        f32x4 accs = (f32x4){0.f, 0.f, 0.f, 0.f};
#pragma unroll
        for (int tap = 0; tap < 9; tap++) {
            const int dh = tap / 3, dw = tap % 3;
            int wpos = px + dw;
#pragma unroll
            for (int ks = 0; ks < 4; ks++) {
                int col = (ks * 32 + kk) ^ (((wpos >> 1) & 7) << 3);
                short8 bv = *(const short8*)(&sB[dh][wpos][col]);
                short8 av = *(const short8*)(Db + ((size_t)tap * 16 + l16) * Cn + ks * 32 + kk);
                accs = __builtin_amdgcn_mfma_f32_16x16x32_bf16(av, bv, accs, 0, 0, 0);
            }
        }
#pragma unroll
        for (int ks = 0; ks < 4; ks++) {
            int col = (ks * 32 + kk) ^ (((px >> 1) & 7) << 3);
            short8 bv = *(const short8*)(&sY[px][col]);
            short8 av = *(const short8*)(wsb + l16 * 256 + 128 + ks * 32 + kk);
            accs = __builtin_amdgcn_mfma_f32_16x16x32_bf16(av, bv, accs, 0, 0, 0);
        }
#pragma unroll
        for (int r = 0; r < 4; r++) {
            int tt = half * 4 + r;
            if (tt < KK)
                sfB[((size_t)b * KK + tt) * HWn + h * Wn + px] = accs[r];
        }
    }
}

// ---------------------------------------------------------------------------
// K4: streaming finish. out[o,p] = T[o,p] + sum_t sf[t,p] * U[o, p+delta_t].
// Block = (b,h), 512 threads; no LDS, no barriers; shfl for w+-1.
// ---------------------------------------------------------------------------
__global__ __launch_bounds__(512) void k_fin(
    const unsigned short* __restrict__ U, const unsigned short* __restrict__ Tb,
    const float* __restrict__ sfB, float* __restrict__ out)
{
    int bid = blockIdx.x;
    int b = bid & 7, h = bid >> 3;
    int t = threadIdx.x;
    int w = t & 63, og = t >> 6;
    bool hm = h > 0, hp = h < Hn - 1;

    float sfw[9];
#pragma unroll
    for (int q = 0; q < 9; q++)
        sfw[q] = sfB[(size_t)(b * KK + q) * HWn + h * Wn + w];

    size_t base = (size_t)(b * Cn + og * 16) * HWn + h * Wn + w;
#pragma unroll
    for (int i = 0; i < 16; i++) {
        const unsigned short* up = U + base + (size_t)i * HWn;
        float r0 = hm ? b2f(up[-Wn]) : 0.f;
        float r1 = b2f(up[0]);
        float r2 = hp ? b2f(up[Wn]) : 0.f;
        float xl0 = __shfl_up(r0, 1), xr0 = __shfl_down(r0, 1);
        float xl1 = __shfl_up(r1, 1), xr1 = __shfl_down(r1, 1);
        float xl2 = __shfl_up(r2, 1), xr2 = __shfl_down(r2, 1);
        if (w == 0)  { xl0 = 0.f; xl1 = 0.f; xl2 = 0.f; }
        if (w == 63) { xr0 = 0.f; xr1 = 0.f; xr2 = 0.f; }
        float a = sfw[0] * xl0 + sfw[1] * r0 + sfw[2] * xr0
                + sfw[3] * xl1 + sfw[4] * r1 + sfw[5] * xr1
                + sfw[6] * xl2 + sfw[7] * r2 + sfw[8] * xr2;
        a += b2f(Tb[base + (size_t)i * HWn]);
        __builtin_nontemporal_store(a, &out[base + (size_t)i * HWn]);
    }
}

// ---------------------------------------------------------------------------
extern "C" void kernel_launch(void* const* d_in, const int* in_sizes, int n_in,
                              void* d_out, int out_size, void* d_ws, size_t ws_size,
                              hipStream_t stream) {
    (void)in_sizes; (void)n_in; (void)out_size; (void)ws_size;
    const float* X2  = (const float*)d_in[0];
    const float* Y2  = (const float*)d_in[1];
    const float* sw  = (const float*)d_in[2];
    const float* w1  = (const float*)d_in[3];
    const float* w2  = (const float*)d_in[4];
    const float* w3  = (const float*)d_in[5];
    const float* wsp = (const float*)d_in[6];
    const float* wf  = (const float*)d_in[7];
    float* out = (float*)d_out;

    // ws layout (float offsets); total ~20.5 MB
    float* wsf = (float*)d_ws;
    unsigned short* Tb = (unsigned short*)wsf;               // 8*128*4096 u16 (8 MB)
    unsigned short* U  = (unsigned short*)(wsf + 2097152);   // 8*128*4096 u16 (8 MB)
    float* sfB = wsf + 4194304;                              // 8*9*4096 f (1.18 MB)
    float* pws = wsf + 4489216;                              // 10240 f
    unsigned short* wfb = (unsigned short*)(wsf + 4499456);  // 32768 u16
    unsigned short* wsb = (unsigned short*)(wsf + 4515840);  // 4096 u16
    unsigned short* Cb  = (unsigned short*)(wsf + 4517888);  // 8*9*128*128 u16 (2.36 MB)
    unsigned short* Db  = (unsigned short*)(wsf + 5107712);  // 9*16*128 u16

    hipLaunchKernelGGL(k_pre, dim3(Bn * Cn), dim3(256), 0, stream, X2, Y2, pws);
    hipLaunchKernelGGL(k_ctx, dim3(32), dim3(256), 0, stream,
                       pws, sw, w1, w2, w3, wf, wsp, wfb, wsb, Cb, Db);
    hipLaunchKernelGGL(k_main, dim3(Bn * Hn), dim3(512), 0, stream,
                       X2, Y2, Cb, Db, wfb, wsb, Tb, U, sfB);
    hipLaunchKernelGGL(k_fin, dim3(Bn * Hn), dim3(512), 0, stream,
                       U, Tb, sfB, out);
}

// Round 12
// 100.195 us; speedup vs baseline: 1.0352x; 1.0352x over previous
//
#include <hip/hip_runtime.h>
#include <hip/hip_bf16.h>

#define Bn 8
#define Cn 128
#define Hn 64
#define Wn 64
#define HWn 4096
#define KK 9

typedef short short8 __attribute__((ext_vector_type(8)));
typedef float f32x4 __attribute__((ext_vector_type(4)));

__device__ inline unsigned short f2b(float v) {
    __hip_bfloat16 h = __float2bfloat16(v);
    return *reinterpret_cast<unsigned short*>(&h);
}
__device__ inline float b2f(unsigned short u) {
    return __uint_as_float(((unsigned int)u) << 16);
}

// ---------------------------------------------------------------------------
// K1: per-(b,c) plane streaming sums (stride 10).
// ---------------------------------------------------------------------------
__global__ __launch_bounds__(256) void k_pre(
    const float* __restrict__ X2, const float* __restrict__ Y2,
    float* __restrict__ pws)
{
    int bc = blockIdx.x, t = threadIdx.x;
    const float4* xp = (const float4*)(X2 + (size_t)bc * HWn);
    const float4* yp = (const float4*)(Y2 + (size_t)bc * HWn);
    float v[10];
#pragma unroll
    for (int k = 0; k < 10; k++) v[k] = 0.f;
#pragma unroll
    for (int i = 0; i < 4; i++) {
        int q = t + i * 256;
        float4 x = xp[q], y = yp[q];
        float s4 = x.x + x.y + x.z + x.w;
        v[0] += s4;
        v[5] += y.x + y.y + y.z + y.w;
        int px = q * 4, h = px >> 6, w4 = px & 63;
        if (h == 0)   v[1] += s4;
        if (h == 63)  v[2] += s4;
        if (w4 == 0)  v[3] += x.x;
        if (w4 == 60) v[4] += x.w;
        if (px == 0)    v[6] += x.x;
        if (px == 60)   v[7] += x.w;
        if (px == 4032) v[8] += x.x;
        if (px == 4092) v[9] += x.w;
    }
#pragma unroll
    for (int k = 0; k < 10; k++)
#pragma unroll
        for (int off = 32; off; off >>= 1)
            v[k] += __shfl_down(v[k], off);
    __shared__ float red[4][10];
    int lane = t & 63, wv = t >> 6;
    if (lane == 0) {
#pragma unroll
        for (int k = 0; k < 10; k++) red[wv][k] = v[k];
    }
    __syncthreads();
    if (t < 10) pws[bc * 10 + t] = red[0][t] + red[1][t] + red[2][t] + red[3][t];
}

// ---------------------------------------------------------------------------
// K2a: MLP only. 8 blocks (one per batch). All reduction loops unrolled so
// loads batch instead of serializing. cf (f32) -> cfG.
// ---------------------------------------------------------------------------
__global__ __launch_bounds__(256) void k_mlp(
    const float* __restrict__ pws, const float* __restrict__ sw,
    const float* __restrict__ w1, const float* __restrict__ w2,
    const float* __restrict__ w3, float* __restrict__ cfG)
{
    int b = blockIdx.x, t = threadIdx.x;
    __shared__ float mfc[256], c1[64], c2[64];
    if (t < 128) {
        const float* S = pws + (b * Cn + t) * 10;
        float T = S[0];
        float R[3]  = { S[2], 0.f, S[1] };
        float Cc[3] = { S[4], 0.f, S[3] };
        float Xc[3][3] = {{S[9], 0.f, S[8]}, {0.f, 0.f, 0.f}, {S[7], 0.f, S[6]}};
        float a = 0.f;
#pragma unroll
        for (int i = 0; i < 3; i++)
#pragma unroll
            for (int j = 0; j < 3; j++)
                a += sw[t * 9 + i * 3 + j] * (T - R[i] - Cc[j] + Xc[i][j]);
        mfc[t] = a * (1.f / HWn);
    } else {
        mfc[t] = pws[(b * Cn + (t - 128)) * 10 + 5] * (1.f / HWn);
    }
    __syncthreads();
    if (t < 64) {
        const float4* wr = (const float4*)(w1 + t * 256);
        float a = 0.f;
#pragma unroll
        for (int c = 0; c < 64; c++) {
            float4 v = wr[c];
            a += v.x * mfc[c*4] + v.y * mfc[c*4+1] + v.z * mfc[c*4+2] + v.w * mfc[c*4+3];
        }
        c1[t] = a;
    }
    __syncthreads();
    if (t < 64) {
        const float4* wr = (const float4*)(w2 + t * 64);
        float a = 0.f;
#pragma unroll
        for (int c = 0; c < 16; c++) {
            float4 v = wr[c];
            a += v.x * c1[c*4] + v.y * c1[c*4+1] + v.z * c1[c*4+2] + v.w * c1[c*4+3];
        }
        c2[t] = fmaxf(a, 0.f);
    }
    __syncthreads();
    for (int j = t; j < Cn * KK; j += 256) {
        const float4* wr = (const float4*)(w3 + j * 64);
        float a = 0.f;
#pragma unroll
        for (int c = 0; c < 16; c++) {
            float4 v = wr[c];
            a += v.x * c2[c*4] + v.y * c2[c*4+1] + v.z * c2[c*4+2] + v.w * c2[c*4+3];
        }
        cfG[b * Cn * KK + j] = a;
    }
}

// ---------------------------------------------------------------------------
// K2b: weight builder. 72 blocks = (b, tap). Pure streaming, unrolled.
//  C[b][tap][o][c] = wf[o][c]*sw[c][tap] + wf[o][128+c]*cf[b][c][tap]
//  b==0: D[tap][s][c] = ws[s][c]*sw[c][tap] (s<9; 9..15 zero)
//  b==1: wfb slice (tap<8); tap==8: wsb
// ---------------------------------------------------------------------------
__global__ __launch_bounds__(256) void k_wb(
    const float* __restrict__ cfG, const float* __restrict__ sw,
    const float* __restrict__ wf, const float* __restrict__ wsp,
    unsigned short* __restrict__ Cb, unsigned short* __restrict__ Db,
    unsigned short* __restrict__ wfb, unsigned short* __restrict__ wsb)
{
    int blk = blockIdx.x, b = blk / 9, tap = blk - b * 9;
    int t = threadIdx.x;
    __shared__ float swcol[Cn], cfcol[Cn];
    if (t < 128) {
        swcol[t] = sw[t * 9 + tap];
        cfcol[t] = cfG[b * Cn * KK + t * 9 + tap];
    }
    __syncthreads();

    {
        int o = t >> 1, ch0 = (t & 1) * 64;
        const float4* wx = (const float4*)(wf + o * 256 + ch0);
        const float4* wd = (const float4*)(wf + o * 256 + 128 + ch0);
        unsigned short tmp[64];
#pragma unroll
        for (int g = 0; g < 16; g++) {
            float4 x = wx[g], d = wd[g];
            int cb = ch0 + g * 4;
            tmp[g*4+0] = f2b(x.x * swcol[cb+0] + d.x * cfcol[cb+0]);
            tmp[g*4+1] = f2b(x.y * swcol[cb+1] + d.y * cfcol[cb+1]);
            tmp[g*4+2] = f2b(x.z * swcol[cb+2] + d.z * cfcol[cb+2]);
            tmp[g*4+3] = f2b(x.w * swcol[cb+3] + d.w * cfcol[cb+3]);
        }
        unsigned short* dst = Cb + (((size_t)blk) * Cn + o) * Cn + ch0;
#pragma unroll
        for (int q = 0; q < 8; q++) ((uint4*)dst)[q] = ((uint4*)tmp)[q];
    }

    if (b == 0 && t < 128) {
        int s = t >> 3, cb = (t & 7) * 16;
        unsigned short tmp[16];
#pragma unroll
        for (int j = 0; j < 16; j++) {
            int c = cb + j;
            float v = (s < KK) ? wsp[s * 256 + c] * swcol[c] : 0.f;
            tmp[j] = f2b(v);
        }
        unsigned short* dst = Db + ((size_t)tap * 16 + s) * Cn + cb;
        ((uint4*)dst)[0] = ((uint4*)tmp)[0];
        ((uint4*)dst)[1] = ((uint4*)tmp)[1];
    }
    if (b == 1) {
        if (tap < 8) {
#pragma unroll
            for (int i = 0; i < 16; i++) {
                int j = tap * 4096 + i * 256 + t;
                wfb[j] = f2b(wf[j]);
            }
        } else {
#pragma unroll
            for (int i = 0; i < 16; i++) {
                int j = i * 256 + t;
                int tt = j >> 8, c = j & 255;
                wsb[j] = (tt < KK) ? f2b(wsp[tt * 256 + c]) : (unsigned short)0;
            }
        }
    }
}

// ---------------------------------------------------------------------------
// K3: THE GEMM. One block per (b,h), 512 threads, 67 KB LDS.
// A-fragment loads hoisted per k-slice (batched, not serialized).
// ---------------------------------------------------------------------------
__global__ __launch_bounds__(512, 2) void k_main(
    const float* __restrict__ X2, const float* __restrict__ Y2,
    const unsigned short* __restrict__ Cb, const unsigned short* __restrict__ Db,
    const unsigned short* __restrict__ wfb, const unsigned short* __restrict__ wsb,
    unsigned short* __restrict__ Tb, unsigned short* __restrict__ U,
    float* __restrict__ sfB)
{
    __shared__ unsigned short sB[3][66][Cn];   // 50.7 KB, col swizzled
    __shared__ unsigned short sY[Wn][Cn];      // 16 KB

    int bid = blockIdx.x, b = bid & 7, h = bid >> 3;
    int t = threadIdx.x;

    for (int idx = t; idx < 768; idx += 512) {
        int r = idx / 256, side = (idx >> 7) & 1, c = idx & 127;
        sB[r][side ? 65 : 0][c] = 0;
    }
    for (int u = t; u < 6144; u += 512) {
        int w4 = u & 15, rc = u >> 4;
        int r = rc % 3, c = rc / 3;
        int hh = h - 1 + r;
        float4 v = (hh >= 0 && hh < Hn)
            ? *(const float4*)(X2 + ((size_t)(b * Cn + c) * HWn + hh * Wn + w4 * 4))
            : (float4){0.f, 0.f, 0.f, 0.f};
        float va[4] = { v.x, v.y, v.z, v.w };
#pragma unroll
        for (int j = 0; j < 4; j++) {
            int wpos = w4 * 4 + j + 1;
            sB[r][wpos][c ^ (((wpos >> 1) & 7) << 3)] = f2b(va[j]);
        }
    }
    for (int u = t; u < 2048; u += 512) {
        int w4 = u & 15, c = u >> 4;
        float4 v = *(const float4*)(Y2 + ((size_t)(b * Cn + c) * HWn + h * Wn + w4 * 4));
        float va[4] = { v.x, v.y, v.z, v.w };
#pragma unroll
        for (int j = 0; j < 4; j++) {
            int w = w4 * 4 + j;
            sY[w][c ^ (((w >> 1) & 7) << 3)] = f2b(va[j]);
        }
    }
    __syncthreads();

    int lane = t & 63, wv = t >> 6;
    int l16 = lane & 15, half = lane >> 4, kk = half * 8;

    if (wv < 4) {
        // ---- T: 32 output rows per wave, all 64 px; A-loads hoisted per ks.
        int o0 = wv * 32;
        const unsigned short* Cbase = Cb + (size_t)b * 9 * Cn * Cn;
        f32x4 acc[2][4];
#pragma unroll
        for (int m = 0; m < 2; m++)
#pragma unroll
            for (int n = 0; n < 4; n++)
                acc[m][n] = (f32x4){0.f, 0.f, 0.f, 0.f};
#pragma unroll
        for (int ks = 0; ks < 4; ks++) {
            short8 av0[9], av1[9];
#pragma unroll
            for (int tap = 0; tap < 9; tap++) {
                const unsigned short* ap = Cbase + ((size_t)tap * Cn) * Cn + ks * 32 + kk;
                av0[tap] = *(const short8*)(ap + (o0 + l16) * Cn);
                av1[tap] = *(const short8*)(ap + (o0 + 16 + l16) * Cn);
            }
#pragma unroll
            for (int tap = 0; tap < 9; tap++) {
                const int dh = tap / 3, dw = tap % 3;
#pragma unroll
                for (int n = 0; n < 4; n++) {
                    int wpos = n * 16 + l16 + dw;
                    int col = (ks * 32 + kk) ^ (((wpos >> 1) & 7) << 3);
                    short8 bv = *(const short8*)(&sB[dh][wpos][col]);
                    acc[0][n] = __builtin_amdgcn_mfma_f32_16x16x32_bf16(av0[tap], bv, acc[0][n], 0, 0, 0);
                    acc[1][n] = __builtin_amdgcn_mfma_f32_16x16x32_bf16(av1[tap], bv, acc[1][n], 0, 0, 0);
                }
            }
        }
#pragma unroll
        for (int m = 0; m < 2; m++)
#pragma unroll
            for (int n = 0; n < 4; n++)
#pragma unroll
                for (int r = 0; r < 4; r++) {
                    int o = o0 + m * 16 + half * 4 + r;
                    Tb[(size_t)(b * Cn + o) * HWn + h * Wn + n * 16 + l16] = f2b(acc[m][n][r]);
                }
    } else {
        // ---- U + sf for px tile (wv-4); A-loads hoisted per ks.
        int n = wv - 4;
        int px = n * 16 + l16;
        f32x4 accu[8];
#pragma unroll
        for (int m = 0; m < 8; m++) accu[m] = (f32x4){0.f, 0.f, 0.f, 0.f};
        {
            int wpos = px + 1;
#pragma unroll
            for (int ks = 0; ks < 4; ks++) {
                short8 av[8];
#pragma unroll
                for (int m = 0; m < 8; m++)
                    av[m] = *(const short8*)(wfb + (m * 16 + l16) * 256 + 128 + ks * 32 + kk);
                int col = (ks * 32 + kk) ^ (((wpos >> 1) & 7) << 3);
                short8 bv = *(const short8*)(&sB[1][wpos][col]);
#pragma unroll
                for (int m = 0; m < 8; m++)
                    accu[m] = __builtin_amdgcn_mfma_f32_16x16x32_bf16(av[m], bv, accu[m], 0, 0, 0);
            }
        }
#pragma unroll
        for (int m = 0; m < 8; m++)
#pragma unroll
            for (int r = 0; r < 4; r++) {
                int o = m * 16 + half * 4 + r;
                U[(size_t)(b * Cn + o) * HWn + h * Wn + px] = f2b(accu[m][r]);
            }
        f32x4 accs = (f32x4){0.f, 0.f, 0.f, 0.f};
#pragma unroll
        for (int ks = 0; ks < 4; ks++) {
            short8 ad[9];
#pragma unroll
            for (int tap = 0; tap < 9; tap++)
                ad[tap] = *(const short8*)(Db + ((size_t)tap * 16 + l16) * Cn + ks * 32 + kk);
            short8 ay = *(const short8*)(wsb + l16 * 256 + 128 + ks * 32 + kk);
#pragma unroll
            for (int tap = 0; tap < 9; tap++) {
                const int dh = tap / 3, dw = tap % 3;
                int wpos = px + dw;
                int col = (ks * 32 + kk) ^ (((wpos >> 1) & 7) << 3);
                short8 bv = *(const short8*)(&sB[dh][wpos][col]);
                accs = __builtin_amdgcn_mfma_f32_16x16x32_bf16(ad[tap], bv, accs, 0, 0, 0);
            }
            int col = (ks * 32 + kk) ^ (((px >> 1) & 7) << 3);
            short8 bv = *(const short8*)(&sY[px][col]);
            accs = __builtin_amdgcn_mfma_f32_16x16x32_bf16(ay, bv, accs, 0, 0, 0);
        }
#pragma unroll
        for (int r = 0; r < 4; r++) {
            int tt = half * 4 + r;
            if (tt < KK)
                sfB[((size_t)b * KK + tt) * HWn + h * Wn + px] = accs[r];
        }
    }
}

// ---------------------------------------------------------------------------
// K4: streaming finish. out[o,p] = T[o,p] + sum_t sf[t,p] * U[o, p+delta_t].
// ---------------------------------------------------------------------------
__global__ __launch_bounds__(512) void k_fin(
    const unsigned short* __restrict__ U, const unsigned short* __restrict__ Tb,
    const float* __restrict__ sfB, float* __restrict__ out)
{
    int bid = blockIdx.x;
    int b = bid & 7, h = bid >> 3;
    int t = threadIdx.x;
    int w = t & 63, og = t >> 6;
    bool hm = h > 0, hp = h < Hn - 1;

    float sfw[9];
#pragma unroll
    for (int q = 0; q < 9; q++)
        sfw[q] = sfB[(size_t)(b * KK + q) * HWn + h * Wn + w];

    size_t base = (size_t)(b * Cn + og * 16) * HWn + h * Wn + w;
#pragma unroll
    for (int i = 0; i < 16; i++) {
        const unsigned short* up = U + base + (size_t)i * HWn;
        float r0 = hm ? b2f(up[-Wn]) : 0.f;
        float r1 = b2f(up[0]);
        float r2 = hp ? b2f(up[Wn]) : 0.f;
        float xl0 = __shfl_up(r0, 1), xr0 = __shfl_down(r0, 1);
        float xl1 = __shfl_up(r1, 1), xr1 = __shfl_down(r1, 1);
        float xl2 = __shfl_up(r2, 1), xr2 = __shfl_down(r2, 1);
        if (w == 0)  { xl0 = 0.f; xl1 = 0.f; xl2 = 0.f; }
        if (w == 63) { xr0 = 0.f; xr1 = 0.f; xr2 = 0.f; }
        float a = sfw[0] * xl0 + sfw[1] * r0 + sfw[2] * xr0
                + sfw[3] * xl1 + sfw[4] * r1 + sfw[5] * xr1
                + sfw[6] * xl2 + sfw[7] * r2 + sfw[8] * xr2;
        a += b2f(Tb[base + (size_t)i * HWn]);
        __builtin_nontemporal_store(a, &out[base + (size_t)i * HWn]);
    }
}

// ---------------------------------------------------------------------------
extern "C" void kernel_launch(void* const* d_in, const int* in_sizes, int n_in,
                              void* d_out, int out_size, void* d_ws, size_t ws_size,
                              hipStream_t stream) {
    (void)in_sizes; (void)n_in; (void)out_size; (void)ws_size;
    const float* X2  = (const float*)d_in[0];
    const float* Y2  = (const float*)d_in[1];
    const float* sw  = (const float*)d_in[2];
    const float* w1  = (const float*)d_in[3];
    const float* w2  = (const float*)d_in[4];
    const float* w3  = (const float*)d_in[5];
    const float* wsp = (const float*)d_in[6];
    const float* wf  = (const float*)d_in[7];
    float* out = (float*)d_out;

    float* wsf = (float*)d_ws;
    unsigned short* Tb = (unsigned short*)wsf;               // 8 MB
    unsigned short* U  = (unsigned short*)(wsf + 2097152);   // 8 MB
    float* sfB = wsf + 4194304;                              // 1.18 MB
    float* pws = wsf + 4489216;                              // 10240 f
    float* cfG = wsf + 4499456;                              // 9216 f
    unsigned short* wfb = (unsigned short*)(wsf + 4508672);  // 32768 u16
    unsigned short* wsb = (unsigned short*)(wsf + 4525056);  // 4096 u16
    unsigned short* Cb  = (unsigned short*)(wsf + 4527104);  // 8*9*128*128 u16
    unsigned short* Db  = (unsigned short*)(wsf + 5116928);  // 9*16*128 u16

    hipLaunchKernelGGL(k_pre, dim3(Bn * Cn), dim3(256), 0, stream, X2, Y2, pws);
    hipLaunchKernelGGL(k_mlp, dim3(Bn), dim3(256), 0, stream,
                       pws, sw, w1, w2, w3, cfG);
    hipLaunchKernelGGL(k_wb, dim3(72), dim3(256), 0, stream,
                       cfG, sw, wf, wsp, Cb, Db, wfb, wsb);
    hipLaunchKernelGGL(k_main, dim3(Bn * Hn), dim3(512), 0, stream,
                       X2, Y2, Cb, Db, wfb, wsb, Tb, U, sfB);
    hipLaunchKernelGGL(k_fin, dim3(Bn * Hn), dim3(512), 0, stream,
                       U, Tb, sfB, out);
}

// Round 13
// 82.130 us; speedup vs baseline: 1.2628x; 1.2200x over previous
//
#include <hip/hip_runtime.h>
#include <hip/hip_bf16.h>

#define Bn 8
#define Cn 128
#define Hn 64
#define Wn 64
#define HWn 4096
#define KK 9

typedef short short8 __attribute__((ext_vector_type(8)));
typedef float f32x4 __attribute__((ext_vector_type(4)));

#define SWZ(px) ((((px) >> 1) & 7) << 3)

__device__ inline unsigned short f2b(float v) {
    __hip_bfloat16 h = __float2bfloat16(v);
    return *reinterpret_cast<unsigned short*>(&h);
}
__device__ inline float b2f(unsigned short u) {
    return __uint_as_float(((unsigned int)u) << 16);
}

// ---------------------------------------------------------------------------
// K1: per-(b,c) plane streaming sums (stride 10):
//  [0]=sum(X2) [1]=row0 [2]=row63 [3]=col0 [4]=col63 [5]=sum(Y2)
//  [6]=x00 [7]=x063 [8]=x630 [9]=x6363
// ---------------------------------------------------------------------------
__global__ __launch_bounds__(256) void k_pre(
    const float* __restrict__ X2, const float* __restrict__ Y2,
    float* __restrict__ pws)
{
    int bc = blockIdx.x, t = threadIdx.x;
    const float4* xp = (const float4*)(X2 + (size_t)bc * HWn);
    const float4* yp = (const float4*)(Y2 + (size_t)bc * HWn);
    float v[10];
#pragma unroll
    for (int k = 0; k < 10; k++) v[k] = 0.f;
#pragma unroll
    for (int i = 0; i < 4; i++) {
        int q = t + i * 256;
        float4 x = xp[q], y = yp[q];
        float s4 = x.x + x.y + x.z + x.w;
        v[0] += s4;
        v[5] += y.x + y.y + y.z + y.w;
        int px = q * 4, h = px >> 6, w4 = px & 63;
        if (h == 0)   v[1] += s4;
        if (h == 63)  v[2] += s4;
        if (w4 == 0)  v[3] += x.x;
        if (w4 == 60) v[4] += x.w;
        if (px == 0)    v[6] += x.x;
        if (px == 60)   v[7] += x.w;
        if (px == 4032) v[8] += x.x;
        if (px == 4092) v[9] += x.w;
    }
#pragma unroll
    for (int k = 0; k < 10; k++)
#pragma unroll
        for (int off = 32; off; off >>= 1)
            v[k] += __shfl_down(v[k], off);
    __shared__ float red[4][10];
    int lane = t & 63, wv = t >> 6;
    if (lane == 0) {
#pragma unroll
        for (int k = 0; k < 10; k++) red[wv][k] = v[k];
    }
    __syncthreads();
    if (t < 10) pws[bc * 10 + t] = red[0][t] + red[1][t] + red[2][t] + red[3][t];
}

// ---------------------------------------------------------------------------
// K2: MLP (unrolled loads) + wfb/wsb conversion slices. 8 blocks (one per b).
// ---------------------------------------------------------------------------
__global__ __launch_bounds__(256) void k_mlp(
    const float* __restrict__ pws, const float* __restrict__ sw,
    const float* __restrict__ w1, const float* __restrict__ w2,
    const float* __restrict__ w3, const float* __restrict__ wf,
    const float* __restrict__ wsp, float* __restrict__ cfG,
    unsigned short* __restrict__ wfb, unsigned short* __restrict__ wsb)
{
    int b = blockIdx.x, t = threadIdx.x;
    // weight conversion slices (1/8 each block)
#pragma unroll
    for (int i = 0; i < 16; i++) {
        int j = b * 4096 + i * 256 + t;
        wfb[j] = f2b(wf[j]);
    }
#pragma unroll
    for (int i = 0; i < 2; i++) {
        int j = b * 512 + i * 256 + t;
        int tt = j >> 8, c = j & 255;
        wsb[j] = (tt < KK) ? f2b(wsp[tt * 256 + c]) : (unsigned short)0;
    }

    __shared__ float mfc[256], c1[64], c2[64];
    if (t < 128) {
        const float* S = pws + (b * Cn + t) * 10;
        float T = S[0];
        float R[3]  = { S[2], 0.f, S[1] };
        float Cc[3] = { S[4], 0.f, S[3] };
        float Xc[3][3] = {{S[9], 0.f, S[8]}, {0.f, 0.f, 0.f}, {S[7], 0.f, S[6]}};
        float a = 0.f;
#pragma unroll
        for (int i = 0; i < 3; i++)
#pragma unroll
            for (int j = 0; j < 3; j++)
                a += sw[t * 9 + i * 3 + j] * (T - R[i] - Cc[j] + Xc[i][j]);
        mfc[t] = a * (1.f / HWn);
    } else {
        mfc[t] = pws[(b * Cn + (t - 128)) * 10 + 5] * (1.f / HWn);
    }
    __syncthreads();
    if (t < 64) {
        const float4* wr = (const float4*)(w1 + t * 256);
        float a = 0.f;
#pragma unroll
        for (int c = 0; c < 64; c++) {
            float4 v = wr[c];
            a += v.x * mfc[c*4] + v.y * mfc[c*4+1] + v.z * mfc[c*4+2] + v.w * mfc[c*4+3];
        }
        c1[t] = a;
    }
    __syncthreads();
    if (t < 64) {
        const float4* wr = (const float4*)(w2 + t * 64);
        float a = 0.f;
#pragma unroll
        for (int c = 0; c < 16; c++) {
            float4 v = wr[c];
            a += v.x * c1[c*4] + v.y * c1[c*4+1] + v.z * c1[c*4+2] + v.w * c1[c*4+3];
        }
        c2[t] = fmaxf(a, 0.f);
    }
    __syncthreads();
    for (int j = t; j < Cn * KK; j += 256) {
        const float4* wr = (const float4*)(w3 + j * 64);
        float a = 0.f;
#pragma unroll
        for (int c = 0; c < 16; c++) {
            float4 v = wr[c];
            a += v.x * c2[c*4] + v.y * c2[c*4+1] + v.z * c2[c*4+2] + v.w * c2[c*4+3];
        }
        cfG[b * Cn * KK + j] = a;
    }
}

// ---------------------------------------------------------------------------
// K3: dual depthwise conv. Block = (b,c): stage X2 plane in LDS, compute
// Xs = conv(X2, sw[c]) and V = conv(X2, cf[b,c]); write bf16 to XV rows
// c (Xs) and 128+c (V).
// ---------------------------------------------------------------------------
__global__ __launch_bounds__(256) void k_conv(
    const float* __restrict__ X2, const float* __restrict__ sw,
    const float* __restrict__ cf, unsigned short* __restrict__ XV)
{
    __shared__ float sP[HWn];
    int bc = blockIdx.x, b = bc >> 7, c = bc & 127, t = threadIdx.x;
    const float4* xp = (const float4*)(X2 + (size_t)bc * HWn);
#pragma unroll
    for (int i = 0; i < 4; i++) {
        int q = t + i * 256;
        ((float4*)sP)[q] = xp[q];
    }
    __syncthreads();

    float wk[9], vk[9];
#pragma unroll
    for (int i = 0; i < 9; i++) {
        wk[i] = sw[c * 9 + i];
        vk[i] = cf[(b * Cn + c) * 9 + i];
    }
    unsigned short* Xs = XV + (size_t)(b * 256 + c) * HWn;
    unsigned short* Vd = XV + (size_t)(b * 256 + 128 + c) * HWn;
#pragma unroll
    for (int g = 0; g < 4; g++) {
        int grp = t + g * 256;
        int h = grp >> 4, w4 = (grp & 15) * 4;
        float o0 = 0.f, o1 = 0.f, o2 = 0.f, o3 = 0.f;
        float p0 = 0.f, p1 = 0.f, p2 = 0.f, p3 = 0.f;
#pragma unroll
        for (int dh = -1; dh <= 1; dh++) {
            int hh = h + dh;
            if (hh < 0 || hh >= Hn) continue;
            const float* row = sP + hh * Wn;
            float4 a = *(const float4*)(row + w4);
            float xm = (w4 > 0)  ? row[w4 - 1] : 0.f;
            float xq = (w4 < 60) ? row[w4 + 4] : 0.f;
            int tb = (dh + 1) * 3;
            float k0 = wk[tb], k1 = wk[tb + 1], k2 = wk[tb + 2];
            float m0 = vk[tb], m1 = vk[tb + 1], m2 = vk[tb + 2];
            o0 += k0 * xm  + k1 * a.x + k2 * a.y;
            o1 += k0 * a.x + k1 * a.y + k2 * a.z;
            o2 += k0 * a.y + k1 * a.z + k2 * a.w;
            o3 += k0 * a.z + k1 * a.w + k2 * xq;
            p0 += m0 * xm  + m1 * a.x + m2 * a.y;
            p1 += m0 * a.x + m1 * a.y + m2 * a.z;
            p2 += m0 * a.y + m1 * a.z + m2 * a.w;
            p3 += m0 * a.z + m1 * a.w + m2 * xq;
        }
        ushort4 pk1 = { f2b(o0), f2b(o1), f2b(o2), f2b(o3) };
        *(ushort4*)(Xs + grp * 4) = pk1;
        ushort4 pk2 = { f2b(p0), f2b(p1), f2b(p2), f2b(p3) };
        *(ushort4*)(Vd + grp * 4) = pk2;
    }
}

// ---------------------------------------------------------------------------
// K4: PURE GEMM, K=128: U[o][px] = wf_d[o][:] @ X2[b][:][px], bf16 out.
// ---------------------------------------------------------------------------
__global__ __launch_bounds__(512, 2) void k_gemmU(
    const float* __restrict__ X2, const unsigned short* __restrict__ wfb,
    unsigned short* __restrict__ U)
{
    __shared__ unsigned short sB[Wn][128];   // 16 KB

    int bid = blockIdx.x;
    int b = bid & 7, chnk = bid >> 3;
    int px0 = chnk * 64;
    int t = threadIdx.x, pq = t & 15, c0 = t >> 4;   // c0 in [0,32)

#pragma unroll
    for (int i = 0; i < 4; i++) {
        int c = c0 + 32 * i;
        float4 v = *(const float4*)(X2 + ((size_t)(b * Cn + c) * HWn + px0 + pq * 4));
        float va[4] = { v.x, v.y, v.z, v.w };
#pragma unroll
        for (int j = 0; j < 4; j++) {
            int px = pq * 4 + j;
            sB[px][c ^ SWZ(px)] = f2b(va[j]);
        }
    }
    __syncthreads();

    int lane = t & 63, wv = t >> 6;
    int l16 = lane & 15, half = lane >> 4, kk = half * 8;
    int o0 = (wv & 3) * 32, pxh = (wv >> 2) * 32;

    f32x4 acc[2][2];
#pragma unroll
    for (int m = 0; m < 2; m++)
#pragma unroll
        for (int n = 0; n < 2; n++)
            acc[m][n] = (f32x4){0.f, 0.f, 0.f, 0.f};

#pragma unroll
    for (int ks = 0; ks < 4; ks++) {
        short8 av[2];
#pragma unroll
        for (int m = 0; m < 2; m++)
            av[m] = *(const short8*)(wfb + (o0 + m * 16 + l16) * 256 + 128 + ks * 32 + kk);
#pragma unroll
        for (int n = 0; n < 2; n++) {
            int px = pxh + n * 16 + l16;
            int col = (ks * 32 + kk) ^ SWZ(px);
            short8 bv = *(const short8*)(&sB[px][0] + col);
#pragma unroll
            for (int m = 0; m < 2; m++)
                acc[m][n] = __builtin_amdgcn_mfma_f32_16x16x32_bf16(av[m], bv, acc[m][n], 0, 0, 0);
        }
    }
#pragma unroll
    for (int m = 0; m < 2; m++)
#pragma unroll
        for (int n = 0; n < 2; n++)
#pragma unroll
            for (int r = 0; r < 4; r++) {
                int o = o0 + m * 16 + half * 4 + r;
                int px = pxh + n * 16 + l16;
                U[(size_t)(b * Cn + o) * HWn + px0 + px] = f2b(acc[m][n][r]);
            }
}

// ---------------------------------------------------------------------------
// K5: PURE GEMM: sf[16][px] = wsb[16][256] @ [Xs;Y2][256][px]. f32 out.
// ---------------------------------------------------------------------------
__global__ __launch_bounds__(256, 4) void k_sf(
    const unsigned short* __restrict__ XV, const float* __restrict__ Y2,
    const unsigned short* __restrict__ wsb, float* __restrict__ sfB)
{
    __shared__ unsigned short sFt[Wn][256];   // 32 KB

    int bid = blockIdx.x;
    int b = bid & 7, chnk = bid >> 3;
    int px0 = chnk * 64;
    int t = threadIdx.x, pq = t & 15, c0 = t >> 4;

#pragma unroll
    for (int i = 0; i < 8; i++) {
        int c = c0 + 16 * i;
        ushort4 xv = *(const ushort4*)(XV + ((size_t)(b * 256 + c) * HWn + px0 + pq * 4));
        const unsigned short* xa = (const unsigned short*)&xv;
        float4 yv = *(const float4*)(Y2 + ((size_t)(b * Cn + c) * HWn + px0 + pq * 4));
        float ya[4] = { yv.x, yv.y, yv.z, yv.w };
#pragma unroll
        for (int j = 0; j < 4; j++) {
            int px = pq * 4 + j;
            sFt[px][c ^ SWZ(px)] = xa[j];
            sFt[px][(128 + c) ^ SWZ(px)] = f2b(ya[j]);
        }
    }
    __syncthreads();

    int lane = t & 63, wv = t >> 6;
    int l16 = lane & 15, half = lane >> 4, kk = half * 8;
    int px = wv * 16 + l16;
    f32x4 acc = (f32x4){0.f, 0.f, 0.f, 0.f};
#pragma unroll
    for (int ks = 0; ks < 8; ks++) {
        short8 av = *(const short8*)(wsb + l16 * 256 + ks * 32 + kk);
        int col = (ks * 32 + kk) ^ SWZ(px);
        short8 bv = *(const short8*)(&sFt[px][0] + col);
        acc = __builtin_amdgcn_mfma_f32_16x16x32_bf16(av, bv, acc, 0, 0, 0);
    }
#pragma unroll
    for (int r = 0; r < 4; r++) {
        int tt = half * 4 + r;
        if (tt < KK)
            sfB[(size_t)(b * KK + tt) * HWn + px0 + px] = acc[r];
    }
}

// ---------------------------------------------------------------------------
// K6: PURE GEMM: W1[o][px] = wfb[128][256] @ XV[256][px], bf16 out.
// ---------------------------------------------------------------------------
__global__ __launch_bounds__(512, 2) void k_gemmW1(
    const unsigned short* __restrict__ XV, const unsigned short* __restrict__ wfb,
    unsigned short* __restrict__ W1)
{
    __shared__ unsigned short sFt[Wn][256];   // 32 KB

    int bid = blockIdx.x;
    int b = bid & 7, chnk = bid >> 3;
    int px0 = chnk * 64;
    int t = threadIdx.x, pq = t & 15, c0 = t >> 4;   // c0 in [0,32)

#pragma unroll
    for (int i = 0; i < 8; i++) {
        int c = c0 + 32 * i;
        ushort4 v = *(const ushort4*)(XV + ((size_t)(b * 256 + c) * HWn + px0 + pq * 4));
        const unsigned short* va = (const unsigned short*)&v;
#pragma unroll
        for (int j = 0; j < 4; j++) {
            int px = pq * 4 + j;
            sFt[px][c ^ SWZ(px)] = va[j];
        }
    }
    __syncthreads();

    int lane = t & 63, wv = t >> 6;
    int l16 = lane & 15, half = lane >> 4, kk = half * 8;
    int o0 = (wv & 3) * 32, pxh = (wv >> 2) * 32;

    f32x4 acc[2][2];
#pragma unroll
    for (int m = 0; m < 2; m++)
#pragma unroll
        for (int n = 0; n < 2; n++)
            acc[m][n] = (f32x4){0.f, 0.f, 0.f, 0.f};

#pragma unroll
    for (int ks = 0; ks < 8; ks++) {
        short8 av[2];
#pragma unroll
        for (int m = 0; m < 2; m++)
            av[m] = *(const short8*)(wfb + (o0 + m * 16 + l16) * 256 + ks * 32 + kk);
#pragma unroll
        for (int n = 0; n < 2; n++) {
            int px = pxh + n * 16 + l16;
            int col = (ks * 32 + kk) ^ SWZ(px);
            short8 bv = *(const short8*)(&sFt[px][0] + col);
#pragma unroll
            for (int m = 0; m < 2; m++)
                acc[m][n] = __builtin_amdgcn_mfma_f32_16x16x32_bf16(av[m], bv, acc[m][n], 0, 0, 0);
        }
    }
#pragma unroll
    for (int m = 0; m < 2; m++)
#pragma unroll
        for (int n = 0; n < 2; n++)
#pragma unroll
            for (int r = 0; r < 4; r++) {
                int o = o0 + m * 16 + half * 4 + r;
                int px = pxh + n * 16 + l16;
                W1[(size_t)(b * Cn + o) * HWn + px0 + px] = f2b(acc[m][n][r]);
            }
}

// ---------------------------------------------------------------------------
// K7: streaming finish. out[o][w] = W1[o][w] + sum_t sf[t][w]*Upad[o][h+dh][w+dw]
// Block = (b,h), 512 threads; no LDS, no barriers; shfl gives w+-1.
// ---------------------------------------------------------------------------
__global__ __launch_bounds__(512) void k_fin(
    const unsigned short* __restrict__ U, const unsigned short* __restrict__ W1,
    const float* __restrict__ sfB, float* __restrict__ out)
{
    int bid = blockIdx.x;
    int b = bid & 7, h = bid >> 3;
    int t = threadIdx.x;
    int w = t & 63, og = t >> 6;        // og in [0,8): o = og*16 + i
    bool hm = h > 0, hp = h < Hn - 1;

    float sfw[9];
#pragma unroll
    for (int q = 0; q < 9; q++)
        sfw[q] = sfB[(size_t)(b * KK + q) * HWn + h * Wn + w];

    size_t base = (size_t)(b * Cn + og * 16) * HWn + h * Wn + w;
#pragma unroll
    for (int i = 0; i < 16; i++) {
        const unsigned short* up = U + base + (size_t)i * HWn;
        float r0 = hm ? b2f(up[-Wn]) : 0.f;
        float r1 = b2f(up[0]);
        float r2 = hp ? b2f(up[Wn]) : 0.f;
        float xl0 = __shfl_up(r0, 1), xr0 = __shfl_down(r0, 1);
        float xl1 = __shfl_up(r1, 1), xr1 = __shfl_down(r1, 1);
        float xl2 = __shfl_up(r2, 1), xr2 = __shfl_down(r2, 1);
        if (w == 0)  { xl0 = 0.f; xl1 = 0.f; xl2 = 0.f; }
        if (w == 63) { xr0 = 0.f; xr1 = 0.f; xr2 = 0.f; }
        float a = sfw[0] * xl0 + sfw[1] * r0 + sfw[2] * xr0
                + sfw[3] * xl1 + sfw[4] * r1 + sfw[5] * xr1
                + sfw[6] * xl2 + sfw[7] * r2 + sfw[8] * xr2;
        a += b2f(W1[base + (size_t)i * HWn]);
        __builtin_nontemporal_store(a, &out[base + (size_t)i * HWn]);
    }
}

// ---------------------------------------------------------------------------
extern "C" void kernel_launch(void* const* d_in, const int* in_sizes, int n_in,
                              void* d_out, int out_size, void* d_ws, size_t ws_size,
                              hipStream_t stream) {
    (void)in_sizes; (void)n_in; (void)out_size; (void)ws_size;
    const float* X2  = (const float*)d_in[0];
    const float* Y2  = (const float*)d_in[1];
    const float* sw  = (const float*)d_in[2];
    const float* w1  = (const float*)d_in[3];
    const float* w2  = (const float*)d_in[4];
    const float* w3  = (const float*)d_in[5];
    const float* wsp = (const float*)d_in[6];
    const float* wf  = (const float*)d_in[7];
    float* out = (float*)d_out;

    // ws layout (float offsets); total ~35 MB.
    float* wsf = (float*)d_ws;
    unsigned short* XV = (unsigned short*)wsf;             // 8*256*4096 u16 (16 MB)
    unsigned short* U  = (unsigned short*)(wsf + 4194304); // 8*128*4096 u16 (8 MB)
    unsigned short* W1 = (unsigned short*)(wsf + 6291456); // 8*128*4096 u16 (8 MB)
    float* sfB = wsf + 8388608;                            // 8*9*4096 f (1.18 MB)
    float* pws = wsf + 8683520;                            // 10240 f
    float* cfG = wsf + 8693760;                            // 9216 f
    unsigned short* wfb = (unsigned short*)(wsf + 8702976); // 32768 u16
    unsigned short* wsb = (unsigned short*)(wsf + 8719360); // 4096 u16

    hipLaunchKernelGGL(k_pre, dim3(Bn * Cn), dim3(256), 0, stream, X2, Y2, pws);
    hipLaunchKernelGGL(k_mlp, dim3(Bn), dim3(256), 0, stream,
                       pws, sw, w1, w2, w3, wf, wsp, cfG, wfb, wsb);
    hipLaunchKernelGGL(k_gemmU, dim3(Bn * 64), dim3(512), 0, stream,
                       X2, wfb, U);
    hipLaunchKernelGGL(k_conv, dim3(Bn * Cn), dim3(256), 0, stream,
                       X2, sw, cfG, XV);
    hipLaunchKernelGGL(k_sf, dim3(Bn * 64), dim3(256), 0, stream,
                       XV, Y2, wsb, sfB);
    hipLaunchKernelGGL(k_gemmW1, dim3(Bn * 64), dim3(512), 0, stream,
                       XV, wfb, W1);
    hipLaunchKernelGGL(k_fin, dim3(Bn * Hn), dim3(512), 0, stream,
                       U, W1, sfB, out);
}

// Round 14
// 73.756 us; speedup vs baseline: 1.4062x; 1.1135x over previous
//
#include <hip/hip_runtime.h>
#include <hip/hip_bf16.h>

#define Bn 8
#define Cn 128
#define Hn 64
#define Wn 64
#define HWn 4096
#define KK 9

typedef short short8 __attribute__((ext_vector_type(8)));
typedef float f32x4 __attribute__((ext_vector_type(4)));

#define SWZ(px) ((((px) >> 1) & 7) << 3)

__device__ inline unsigned short f2b(float v) {
    __hip_bfloat16 h = __float2bfloat16(v);
    return *reinterpret_cast<unsigned short*>(&h);
}
__device__ inline float b2f(unsigned short u) {
    return __uint_as_float(((unsigned int)u) << 16);
}

// ---------------------------------------------------------------------------
// K1: per-(b,c) plane streaming sums (stride 10) + wfb/wsb bf16 conversion
// slices (blocks 0..143, one 256-elem slice each; independent of pws).
// ---------------------------------------------------------------------------
__global__ __launch_bounds__(256) void k_pre(
    const float* __restrict__ X2, const float* __restrict__ Y2,
    const float* __restrict__ wf, const float* __restrict__ wsp,
    float* __restrict__ pws,
    unsigned short* __restrict__ wfb, unsigned short* __restrict__ wsb)
{
    int bc = blockIdx.x, t = threadIdx.x;
    if (bc < 128) {
        int j = bc * 256 + t;
        wfb[j] = f2b(wf[j]);
    } else if (bc < 144) {
        int row = bc - 128;
        wsb[row * 256 + t] = (row < KK) ? f2b(wsp[row * 256 + t]) : (unsigned short)0;
    }

    const float4* xp = (const float4*)(X2 + (size_t)bc * HWn);
    const float4* yp = (const float4*)(Y2 + (size_t)bc * HWn);
    float v[10];
#pragma unroll
    for (int k = 0; k < 10; k++) v[k] = 0.f;
#pragma unroll
    for (int i = 0; i < 4; i++) {
        int q = t + i * 256;
        float4 x = xp[q], y = yp[q];
        float s4 = x.x + x.y + x.z + x.w;
        v[0] += s4;
        v[5] += y.x + y.y + y.z + y.w;
        int px = q * 4, h = px >> 6, w4 = px & 63;
        if (h == 0)   v[1] += s4;
        if (h == 63)  v[2] += s4;
        if (w4 == 0)  v[3] += x.x;
        if (w4 == 60) v[4] += x.w;
        if (px == 0)    v[6] += x.x;
        if (px == 60)   v[7] += x.w;
        if (px == 4032) v[8] += x.x;
        if (px == 4092) v[9] += x.w;
    }
#pragma unroll
    for (int k = 0; k < 10; k++)
#pragma unroll
        for (int off = 32; off; off >>= 1)
            v[k] += __shfl_down(v[k], off);
    __shared__ float red[4][10];
    int lane = t & 63, wv = t >> 6;
    if (lane == 0) {
#pragma unroll
        for (int k = 0; k < 10; k++) red[wv][k] = v[k];
    }
    __syncthreads();
    if (t < 10) pws[bc * 10 + t] = red[0][t] + red[1][t] + red[2][t] + red[3][t];
}

// ---------------------------------------------------------------------------
// K2: MLP (unrolled loads). 8 blocks. -> cfG
// ---------------------------------------------------------------------------
__global__ __launch_bounds__(256) void k_mlp(
    const float* __restrict__ pws, const float* __restrict__ sw,
    const float* __restrict__ w1, const float* __restrict__ w2,
    const float* __restrict__ w3, float* __restrict__ cfG)
{
    int b = blockIdx.x, t = threadIdx.x;
    __shared__ float mfc[256], c1[64], c2[64];
    if (t < 128) {
        const float* S = pws + (b * Cn + t) * 10;
        float T = S[0];
        float R[3]  = { S[2], 0.f, S[1] };
        float Cc[3] = { S[4], 0.f, S[3] };
        float Xc[3][3] = {{S[9], 0.f, S[8]}, {0.f, 0.f, 0.f}, {S[7], 0.f, S[6]}};
        float a = 0.f;
#pragma unroll
        for (int i = 0; i < 3; i++)
#pragma unroll
            for (int j = 0; j < 3; j++)
                a += sw[t * 9 + i * 3 + j] * (T - R[i] - Cc[j] + Xc[i][j]);
        mfc[t] = a * (1.f / HWn);
    } else {
        mfc[t] = pws[(b * Cn + (t - 128)) * 10 + 5] * (1.f / HWn);
    }
    __syncthreads();
    if (t < 64) {
        const float4* wr = (const float4*)(w1 + t * 256);
        float a = 0.f;
#pragma unroll
        for (int c = 0; c < 64; c++) {
            float4 v = wr[c];
            a += v.x * mfc[c*4] + v.y * mfc[c*4+1] + v.z * mfc[c*4+2] + v.w * mfc[c*4+3];
        }
        c1[t] = a;
    }
    __syncthreads();
    if (t < 64) {
        const float4* wr = (const float4*)(w2 + t * 64);
        float a = 0.f;
#pragma unroll
        for (int c = 0; c < 16; c++) {
            float4 v = wr[c];
            a += v.x * c1[c*4] + v.y * c1[c*4+1] + v.z * c1[c*4+2] + v.w * c1[c*4+3];
        }
        c2[t] = fmaxf(a, 0.f);
    }
    __syncthreads();
    for (int j = t; j < Cn * KK; j += 256) {
        const float4* wr = (const float4*)(w3 + j * 64);
        float a = 0.f;
#pragma unroll
        for (int c = 0; c < 16; c++) {
            float4 v = wr[c];
            a += v.x * c2[c*4] + v.y * c2[c*4+1] + v.z * c2[c*4+2] + v.w * c2[c*4+3];
        }
        cfG[b * Cn * KK + j] = a;
    }
}

// ---------------------------------------------------------------------------
// K3: grid-partitioned: blocks [0,1024) dual depthwise conv -> XV;
// blocks [1024,1536) K=128 GEMM U = wf_d @ X2. Shared 16 KB LDS union.
// ---------------------------------------------------------------------------
__global__ __launch_bounds__(256) void k_convU(
    const float* __restrict__ X2, const float* __restrict__ sw,
    const float* __restrict__ cf, const unsigned short* __restrict__ wfb,
    unsigned short* __restrict__ XV, unsigned short* __restrict__ U)
{
    __shared__ float sP[HWn];   // 16 KB; gemmU part reuses as u16 [64][128]
    int bid = blockIdx.x, t = threadIdx.x;

    if (bid < 1024) {
        // ---- dual depthwise conv (proven k_conv)
        int bc = bid, b = bc >> 7, c = bc & 127;
        const float4* xp = (const float4*)(X2 + (size_t)bc * HWn);
#pragma unroll
        for (int i = 0; i < 4; i++) {
            int q = t + i * 256;
            ((float4*)sP)[q] = xp[q];
        }
        __syncthreads();

        float wk[9], vk[9];
#pragma unroll
        for (int i = 0; i < 9; i++) {
            wk[i] = sw[c * 9 + i];
            vk[i] = cf[(b * Cn + c) * 9 + i];
        }
        unsigned short* Xs = XV + (size_t)(b * 256 + c) * HWn;
        unsigned short* Vd = XV + (size_t)(b * 256 + 128 + c) * HWn;
#pragma unroll
        for (int g = 0; g < 4; g++) {
            int grp = t + g * 256;
            int h = grp >> 4, w4 = (grp & 15) * 4;
            float o0 = 0.f, o1 = 0.f, o2 = 0.f, o3 = 0.f;
            float p0 = 0.f, p1 = 0.f, p2 = 0.f, p3 = 0.f;
#pragma unroll
            for (int dh = -1; dh <= 1; dh++) {
                int hh = h + dh;
                if (hh < 0 || hh >= Hn) continue;
                const float* row = sP + hh * Wn;
                float4 a = *(const float4*)(row + w4);
                float xm = (w4 > 0)  ? row[w4 - 1] : 0.f;
                float xq = (w4 < 60) ? row[w4 + 4] : 0.f;
                int tb = (dh + 1) * 3;
                float k0 = wk[tb], k1 = wk[tb + 1], k2 = wk[tb + 2];
                float m0 = vk[tb], m1 = vk[tb + 1], m2 = vk[tb + 2];
                o0 += k0 * xm  + k1 * a.x + k2 * a.y;
                o1 += k0 * a.x + k1 * a.y + k2 * a.z;
                o2 += k0 * a.y + k1 * a.z + k2 * a.w;
                o3 += k0 * a.z + k1 * a.w + k2 * xq;
                p0 += m0 * xm  + m1 * a.x + m2 * a.y;
                p1 += m0 * a.x + m1 * a.y + m2 * a.z;
                p2 += m0 * a.y + m1 * a.z + m2 * a.w;
                p3 += m0 * a.z + m1 * a.w + m2 * xq;
            }
            ushort4 pk1 = { f2b(o0), f2b(o1), f2b(o2), f2b(o3) };
            *(ushort4*)(Xs + grp * 4) = pk1;
            ushort4 pk2 = { f2b(p0), f2b(p1), f2b(p2), f2b(p3) };
            *(ushort4*)(Vd + grp * 4) = pk2;
        }
    } else {
        // ---- U GEMM (proven k_gemmU, retiled for 256 threads)
        int bid2 = bid - 1024;
        int b = bid2 & 7, chnk = bid2 >> 3;
        int px0 = chnk * 64;
        unsigned short* sB = (unsigned short*)sP;   // [64][128] swizzled
        int pq = t & 15, c0 = t >> 4;               // c0 in [0,16)
#pragma unroll
        for (int i = 0; i < 8; i++) {
            int c = c0 + 16 * i;
            float4 v = *(const float4*)(X2 + ((size_t)(b * Cn + c) * HWn + px0 + pq * 4));
            float va[4] = { v.x, v.y, v.z, v.w };
#pragma unroll
            for (int j = 0; j < 4; j++) {
                int px = pq * 4 + j;
                sB[px * 128 + (c ^ SWZ(px))] = f2b(va[j]);
            }
        }
        __syncthreads();

        int lane = t & 63, wv = t >> 6;
        int l16 = lane & 15, half = lane >> 4, kk = half * 8;
        int o0 = (wv & 1) * 64, pxh = (wv >> 1) * 32;

        f32x4 acc[4][2];
#pragma unroll
        for (int m = 0; m < 4; m++)
#pragma unroll
            for (int n = 0; n < 2; n++)
                acc[m][n] = (f32x4){0.f, 0.f, 0.f, 0.f};

#pragma unroll
        for (int ks = 0; ks < 4; ks++) {
            short8 av[4];
#pragma unroll
            for (int m = 0; m < 4; m++)
                av[m] = *(const short8*)(wfb + (o0 + m * 16 + l16) * 256 + 128 + ks * 32 + kk);
#pragma unroll
            for (int n = 0; n < 2; n++) {
                int px = pxh + n * 16 + l16;
                int col = (ks * 32 + kk) ^ SWZ(px);
                short8 bv = *(const short8*)(sB + px * 128 + col);
#pragma unroll
                for (int m = 0; m < 4; m++)
                    acc[m][n] = __builtin_amdgcn_mfma_f32_16x16x32_bf16(av[m], bv, acc[m][n], 0, 0, 0);
            }
        }
#pragma unroll
        for (int m = 0; m < 4; m++)
#pragma unroll
            for (int n = 0; n < 2; n++)
#pragma unroll
                for (int r = 0; r < 4; r++) {
                    int o = o0 + m * 16 + half * 4 + r;
                    int px = pxh + n * 16 + l16;
                    U[(size_t)(b * Cn + o) * HWn + px0 + px] = f2b(acc[m][n][r]);
                }
    }
}

// ---------------------------------------------------------------------------
// K4: fused sf + W1 GEMMs off one staging: stage XV[256][64] + Y2[128][64]
// (bf16, swizzled). 512 threads, 48 KB LDS.
//   W1[o][px] = wfb[128][256] @ XV        (all 8 waves, o 32 x px 32 tiles)
//   sf[16][px] = wsb[16][256] @ [Xs;Y2]   (waves 4..7, px 16-chunks)
// ---------------------------------------------------------------------------
__global__ __launch_bounds__(512, 2) void k_sfW1(
    const unsigned short* __restrict__ XV, const float* __restrict__ Y2,
    const unsigned short* __restrict__ wfb, const unsigned short* __restrict__ wsb,
    unsigned short* __restrict__ W1, float* __restrict__ sfB)
{
    __shared__ unsigned short sFt[Wn][256];   // 32 KB  (XV, swizzled)
    __shared__ unsigned short sY[Wn][128];    // 16 KB  (Y2 bf16, swizzled)

    int bid = blockIdx.x;
    int b = bid & 7, chnk = bid >> 3;
    int px0 = chnk * 64;
    int t = threadIdx.x, pq = t & 15, c0 = t >> 4;   // c0 in [0,32)

#pragma unroll
    for (int i = 0; i < 8; i++) {
        int c = c0 + 32 * i;
        ushort4 v = *(const ushort4*)(XV + ((size_t)(b * 256 + c) * HWn + px0 + pq * 4));
        const unsigned short* va = (const unsigned short*)&v;
#pragma unroll
        for (int j = 0; j < 4; j++) {
            int px = pq * 4 + j;
            sFt[px][c ^ SWZ(px)] = va[j];
        }
    }
#pragma unroll
    for (int i = 0; i < 4; i++) {
        int c = c0 + 32 * i;
        float4 v = *(const float4*)(Y2 + ((size_t)(b * Cn + c) * HWn + px0 + pq * 4));
        float va[4] = { v.x, v.y, v.z, v.w };
#pragma unroll
        for (int j = 0; j < 4; j++) {
            int px = pq * 4 + j;
            sY[px][c ^ SWZ(px)] = f2b(va[j]);
        }
    }
    __syncthreads();

    int lane = t & 63, wv = t >> 6;
    int l16 = lane & 15, half = lane >> 4, kk = half * 8;

    // ---- W1 tile: o0 = (wv&3)*32, pxh = (wv>>2)*32
    {
        int o0 = (wv & 3) * 32, pxh = (wv >> 2) * 32;
        f32x4 acc[2][2];
#pragma unroll
        for (int m = 0; m < 2; m++)
#pragma unroll
            for (int n = 0; n < 2; n++)
                acc[m][n] = (f32x4){0.f, 0.f, 0.f, 0.f};
#pragma unroll
        for (int ks = 0; ks < 8; ks++) {
            short8 av[2];
#pragma unroll
            for (int m = 0; m < 2; m++)
                av[m] = *(const short8*)(wfb + (o0 + m * 16 + l16) * 256 + ks * 32 + kk);
#pragma unroll
            for (int n = 0; n < 2; n++) {
                int px = pxh + n * 16 + l16;
                int col = (ks * 32 + kk) ^ SWZ(px);
                short8 bv = *(const short8*)(&sFt[px][0] + col);
#pragma unroll
                for (int m = 0; m < 2; m++)
                    acc[m][n] = __builtin_amdgcn_mfma_f32_16x16x32_bf16(av[m], bv, acc[m][n], 0, 0, 0);
            }
        }
#pragma unroll
        for (int m = 0; m < 2; m++)
#pragma unroll
            for (int n = 0; n < 2; n++)
#pragma unroll
                for (int r = 0; r < 4; r++) {
                    int o = o0 + m * 16 + half * 4 + r;
                    int px = pxh + n * 16 + l16;
                    W1[(size_t)(b * Cn + o) * HWn + px0 + px] = f2b(acc[m][n][r]);
                }
    }

    // ---- sf tile: waves 4..7, px 16-chunk each; B = [Xs (sFt rows c<128); Y2]
    if (wv >= 4) {
        int px = (wv - 4) * 16 + l16;
        f32x4 acc = (f32x4){0.f, 0.f, 0.f, 0.f};
#pragma unroll
        for (int ks = 0; ks < 4; ks++) {
            short8 av = *(const short8*)(wsb + l16 * 256 + ks * 32 + kk);
            int col = (ks * 32 + kk) ^ SWZ(px);
            short8 bv = *(const short8*)(&sFt[px][0] + col);
            acc = __builtin_amdgcn_mfma_f32_16x16x32_bf16(av, bv, acc, 0, 0, 0);
        }
#pragma unroll
        for (int ks = 0; ks < 4; ks++) {
            short8 av = *(const short8*)(wsb + l16 * 256 + 128 + ks * 32 + kk);
            int col = (ks * 32 + kk) ^ SWZ(px);
            short8 bv = *(const short8*)(&sY[px][0] + col);
            acc = __builtin_amdgcn_mfma_f32_16x16x32_bf16(av, bv, acc, 0, 0, 0);
        }
#pragma unroll
        for (int r = 0; r < 4; r++) {
            int tt = half * 4 + r;
            if (tt < KK)
                sfB[(size_t)(b * KK + tt) * HWn + px0 + px] = acc[r];
        }
    }
}

// ---------------------------------------------------------------------------
// K5: streaming finish. out[o][w] = W1[o][w] + sum_t sf[t][w]*Upad[o][h+dh][w+dw]
// ---------------------------------------------------------------------------
__global__ __launch_bounds__(512) void k_fin(
    const unsigned short* __restrict__ U, const unsigned short* __restrict__ W1,
    const float* __restrict__ sfB, float* __restrict__ out)
{
    int bid = blockIdx.x;
    int b = bid & 7, h = bid >> 3;
    int t = threadIdx.x;
    int w = t & 63, og = t >> 6;
    bool hm = h > 0, hp = h < Hn - 1;

    float sfw[9];
#pragma unroll
    for (int q = 0; q < 9; q++)
        sfw[q] = sfB[(size_t)(b * KK + q) * HWn + h * Wn + w];

    size_t base = (size_t)(b * Cn + og * 16) * HWn + h * Wn + w;
#pragma unroll
    for (int i = 0; i < 16; i++) {
        const unsigned short* up = U + base + (size_t)i * HWn;
        float r0 = hm ? b2f(up[-Wn]) : 0.f;
        float r1 = b2f(up[0]);
        float r2 = hp ? b2f(up[Wn]) : 0.f;
        float xl0 = __shfl_up(r0, 1), xr0 = __shfl_down(r0, 1);
        float xl1 = __shfl_up(r1, 1), xr1 = __shfl_down(r1, 1);
        float xl2 = __shfl_up(r2, 1), xr2 = __shfl_down(r2, 1);
        if (w == 0)  { xl0 = 0.f; xl1 = 0.f; xl2 = 0.f; }
        if (w == 63) { xr0 = 0.f; xr1 = 0.f; xr2 = 0.f; }
        float a = sfw[0] * xl0 + sfw[1] * r0 + sfw[2] * xr0
                + sfw[3] * xl1 + sfw[4] * r1 + sfw[5] * xr1
                + sfw[6] * xl2 + sfw[7] * r2 + sfw[8] * xr2;
        a += b2f(W1[base + (size_t)i * HWn]);
        __builtin_nontemporal_store(a, &out[base + (size_t)i * HWn]);
    }
}

// ---------------------------------------------------------------------------
extern "C" void kernel_launch(void* const* d_in, const int* in_sizes, int n_in,
                              void* d_out, int out_size, void* d_ws, size_t ws_size,
                              hipStream_t stream) {
    (void)in_sizes; (void)n_in; (void)out_size; (void)ws_size;
    const float* X2  = (const float*)d_in[0];
    const float* Y2  = (const float*)d_in[1];
    const float* sw  = (const float*)d_in[2];
    const float* w1  = (const float*)d_in[3];
    const float* w2  = (const float*)d_in[4];
    const float* w3  = (const float*)d_in[5];
    const float* wsp = (const float*)d_in[6];
    const float* wf  = (const float*)d_in[7];
    float* out = (float*)d_out;

    float* wsf = (float*)d_ws;
    unsigned short* XV = (unsigned short*)wsf;             // 16 MB
    unsigned short* U  = (unsigned short*)(wsf + 4194304); // 8 MB
    unsigned short* W1 = (unsigned short*)(wsf + 6291456); // 8 MB
    float* sfB = wsf + 8388608;                            // 1.18 MB
    float* pws = wsf + 8683520;                            // 10240 f
    float* cfG = wsf + 8693760;                            // 9216 f
    unsigned short* wfb = (unsigned short*)(wsf + 8702976); // 32768 u16
    unsigned short* wsb = (unsigned short*)(wsf + 8719360); // 4096 u16

    hipLaunchKernelGGL(k_pre, dim3(Bn * Cn), dim3(256), 0, stream,
                       X2, Y2, wf, wsp, pws, wfb, wsb);
    hipLaunchKernelGGL(k_mlp, dim3(Bn), dim3(256), 0, stream,
                       pws, sw, w1, w2, w3, cfG);
    hipLaunchKernelGGL(k_convU, dim3(1536), dim3(256), 0, stream,
                       X2, sw, cfG, wfb, XV, U);
    hipLaunchKernelGGL(k_sfW1, dim3(Bn * 64), dim3(512), 0, stream,
                       XV, Y2, wfb, wsb, W1, sfB);
    hipLaunchKernelGGL(k_fin, dim3(Bn * Hn), dim3(512), 0, stream,
                       U, W1, sfB, out);
}

// Round 15
// 68.470 us; speedup vs baseline: 1.5148x; 1.0772x over previous
//
#include <hip/hip_runtime.h>
#include <hip/hip_bf16.h>

#define Bn 8
#define Cn 128
#define Hn 64
#define Wn 64
#define HWn 4096
#define KK 9

typedef short short8 __attribute__((ext_vector_type(8)));
typedef float f32x4 __attribute__((ext_vector_type(4)));

#define SWZ(px) ((((px) >> 1) & 7) << 3)

__device__ inline unsigned short f2b(float v) {
    __hip_bfloat16 h = __float2bfloat16(v);
    return *reinterpret_cast<unsigned short*>(&h);
}
__device__ inline float b2f(unsigned short u) {
    return __uint_as_float(((unsigned int)u) << 16);
}

// ---------------------------------------------------------------------------
// K1: per-(b,c) plane streaming sums (stride 10) + wfb/wsb bf16 conversion
// slices (blocks 0..143).
// ---------------------------------------------------------------------------
__global__ __launch_bounds__(256) void k_pre(
    const float* __restrict__ X2, const float* __restrict__ Y2,
    const float* __restrict__ wf, const float* __restrict__ wsp,
    float* __restrict__ pws,
    unsigned short* __restrict__ wfb, unsigned short* __restrict__ wsb)
{
    int bc = blockIdx.x, t = threadIdx.x;
    if (bc < 128) {
        int j = bc * 256 + t;
        wfb[j] = f2b(wf[j]);
    } else if (bc < 144) {
        int row = bc - 128;
        wsb[row * 256 + t] = (row < KK) ? f2b(wsp[row * 256 + t]) : (unsigned short)0;
    }

    const float4* xp = (const float4*)(X2 + (size_t)bc * HWn);
    const float4* yp = (const float4*)(Y2 + (size_t)bc * HWn);
    float v[10];
#pragma unroll
    for (int k = 0; k < 10; k++) v[k] = 0.f;
#pragma unroll
    for (int i = 0; i < 4; i++) {
        int q = t + i * 256;
        float4 x = xp[q], y = yp[q];
        float s4 = x.x + x.y + x.z + x.w;
        v[0] += s4;
        v[5] += y.x + y.y + y.z + y.w;
        int px = q * 4, h = px >> 6, w4 = px & 63;
        if (h == 0)   v[1] += s4;
        if (h == 63)  v[2] += s4;
        if (w4 == 0)  v[3] += x.x;
        if (w4 == 60) v[4] += x.w;
        if (px == 0)    v[6] += x.x;
        if (px == 60)   v[7] += x.w;
        if (px == 4032) v[8] += x.x;
        if (px == 4092) v[9] += x.w;
    }
#pragma unroll
    for (int k = 0; k < 10; k++)
#pragma unroll
        for (int off = 32; off; off >>= 1)
            v[k] += __shfl_down(v[k], off);
    __shared__ float red[4][10];
    int lane = t & 63, wv = t >> 6;
    if (lane == 0) {
#pragma unroll
        for (int k = 0; k < 10; k++) red[wv][k] = v[k];
    }
    __syncthreads();
    if (t < 10) pws[bc * 10 + t] = red[0][t] + red[1][t] + red[2][t] + red[3][t];
}

// ---------------------------------------------------------------------------
// K2: grid-partitioned. Blocks 0..7: MLP -> cfG. Blocks 8..519: U GEMM
// (U = wf_d @ X2, K=128), independent of the MLP.
// ---------------------------------------------------------------------------
__global__ __launch_bounds__(256) void k_mlpU(
    const float* __restrict__ pws, const float* __restrict__ sw,
    const float* __restrict__ w1, const float* __restrict__ w2,
    const float* __restrict__ w3, const float* __restrict__ X2,
    const unsigned short* __restrict__ wfb,
    float* __restrict__ cfG, unsigned short* __restrict__ U)
{
    __shared__ float sBuf[4096];   // 16 KB union
    int bid = blockIdx.x, t = threadIdx.x;

    if (bid < 8) {
        int b = bid;
        float* mfc = sBuf;         // 256
        float* c1  = sBuf + 256;   // 64
        float* c2  = sBuf + 320;   // 64
        if (t < 128) {
            const float* S = pws + (b * Cn + t) * 10;
            float T = S[0];
            float R[3]  = { S[2], 0.f, S[1] };
            float Cc[3] = { S[4], 0.f, S[3] };
            float Xc[3][3] = {{S[9], 0.f, S[8]}, {0.f, 0.f, 0.f}, {S[7], 0.f, S[6]}};
            float a = 0.f;
#pragma unroll
            for (int i = 0; i < 3; i++)
#pragma unroll
                for (int j = 0; j < 3; j++)
                    a += sw[t * 9 + i * 3 + j] * (T - R[i] - Cc[j] + Xc[i][j]);
            mfc[t] = a * (1.f / HWn);
        } else {
            mfc[t] = pws[(b * Cn + (t - 128)) * 10 + 5] * (1.f / HWn);
        }
        __syncthreads();
        if (t < 64) {
            const float4* wr = (const float4*)(w1 + t * 256);
            float a = 0.f;
#pragma unroll
            for (int c = 0; c < 64; c++) {
                float4 v = wr[c];
                a += v.x * mfc[c*4] + v.y * mfc[c*4+1] + v.z * mfc[c*4+2] + v.w * mfc[c*4+3];
            }
            c1[t] = a;
        }
        __syncthreads();
        if (t < 64) {
            const float4* wr = (const float4*)(w2 + t * 64);
            float a = 0.f;
#pragma unroll
            for (int c = 0; c < 16; c++) {
                float4 v = wr[c];
                a += v.x * c1[c*4] + v.y * c1[c*4+1] + v.z * c1[c*4+2] + v.w * c1[c*4+3];
            }
            c2[t] = fmaxf(a, 0.f);
        }
        __syncthreads();
        for (int j = t; j < Cn * KK; j += 256) {
            const float4* wr = (const float4*)(w3 + j * 64);
            float a = 0.f;
#pragma unroll
            for (int c = 0; c < 16; c++) {
                float4 v = wr[c];
                a += v.x * c2[c*4] + v.y * c2[c*4+1] + v.z * c2[c*4+2] + v.w * c2[c*4+3];
            }
            cfG[b * Cn * KK + j] = a;
        }
    } else {
        // ---- U GEMM (proven), 256 threads, 16 KB LDS
        int bid2 = bid - 8;
        int b = bid2 & 7, chnk = bid2 >> 3;
        int px0 = chnk * 64;
        unsigned short* sB = (unsigned short*)sBuf;   // [64][128] swizzled
        int pq = t & 15, c0 = t >> 4;                 // c0 in [0,16)
#pragma unroll
        for (int i = 0; i < 8; i++) {
            int c = c0 + 16 * i;
            float4 v = *(const float4*)(X2 + ((size_t)(b * Cn + c) * HWn + px0 + pq * 4));
            float va[4] = { v.x, v.y, v.z, v.w };
#pragma unroll
            for (int j = 0; j < 4; j++) {
                int px = pq * 4 + j;
                sB[px * 128 + (c ^ SWZ(px))] = f2b(va[j]);
            }
        }
        __syncthreads();

        int lane = t & 63, wv = t >> 6;
        int l16 = lane & 15, half = lane >> 4, kk = half * 8;
        int o0 = (wv & 1) * 64, pxh = (wv >> 1) * 32;

        f32x4 acc[4][2];
#pragma unroll
        for (int m = 0; m < 4; m++)
#pragma unroll
            for (int n = 0; n < 2; n++)
                acc[m][n] = (f32x4){0.f, 0.f, 0.f, 0.f};

#pragma unroll
        for (int ks = 0; ks < 4; ks++) {
            short8 av[4];
#pragma unroll
            for (int m = 0; m < 4; m++)
                av[m] = *(const short8*)(wfb + (o0 + m * 16 + l16) * 256 + 128 + ks * 32 + kk);
#pragma unroll
            for (int n = 0; n < 2; n++) {
                int px = pxh + n * 16 + l16;
                int col = (ks * 32 + kk) ^ SWZ(px);
                short8 bv = *(const short8*)(sB + px * 128 + col);
#pragma unroll
                for (int m = 0; m < 4; m++)
                    acc[m][n] = __builtin_amdgcn_mfma_f32_16x16x32_bf16(av[m], bv, acc[m][n], 0, 0, 0);
            }
        }
#pragma unroll
        for (int m = 0; m < 4; m++)
#pragma unroll
            for (int n = 0; n < 2; n++)
#pragma unroll
                for (int r = 0; r < 4; r++) {
                    int o = o0 + m * 16 + half * 4 + r;
                    int px = pxh + n * 16 + l16;
                    U[(size_t)(b * Cn + o) * HWn + px0 + px] = f2b(acc[m][n][r]);
                }
    }
}

// ---------------------------------------------------------------------------
// K3: dual depthwise conv (proven). Block = (b,c) -> XV rows c, 128+c.
// ---------------------------------------------------------------------------
__global__ __launch_bounds__(256) void k_conv(
    const float* __restrict__ X2, const float* __restrict__ sw,
    const float* __restrict__ cf, unsigned short* __restrict__ XV)
{
    __shared__ float sP[HWn];
    int bc = blockIdx.x, b = bc >> 7, c = bc & 127, t = threadIdx.x;
    const float4* xp = (const float4*)(X2 + (size_t)bc * HWn);
#pragma unroll
    for (int i = 0; i < 4; i++) {
        int q = t + i * 256;
        ((float4*)sP)[q] = xp[q];
    }
    __syncthreads();

    float wk[9], vk[9];
#pragma unroll
    for (int i = 0; i < 9; i++) {
        wk[i] = sw[c * 9 + i];
        vk[i] = cf[(b * Cn + c) * 9 + i];
    }
    unsigned short* Xs = XV + (size_t)(b * 256 + c) * HWn;
    unsigned short* Vd = XV + (size_t)(b * 256 + 128 + c) * HWn;
#pragma unroll
    for (int g = 0; g < 4; g++) {
        int grp = t + g * 256;
        int h = grp >> 4, w4 = (grp & 15) * 4;
        float o0 = 0.f, o1 = 0.f, o2 = 0.f, o3 = 0.f;
        float p0 = 0.f, p1 = 0.f, p2 = 0.f, p3 = 0.f;
#pragma unroll
        for (int dh = -1; dh <= 1; dh++) {
            int hh = h + dh;
            if (hh < 0 || hh >= Hn) continue;
            const float* row = sP + hh * Wn;
            float4 a = *(const float4*)(row + w4);
            float xm = (w4 > 0)  ? row[w4 - 1] : 0.f;
            float xq = (w4 < 60) ? row[w4 + 4] : 0.f;
            int tb = (dh + 1) * 3;
            float k0 = wk[tb], k1 = wk[tb + 1], k2 = wk[tb + 2];
            float m0 = vk[tb], m1 = vk[tb + 1], m2 = vk[tb + 2];
            o0 += k0 * xm  + k1 * a.x + k2 * a.y;
            o1 += k0 * a.x + k1 * a.y + k2 * a.z;
            o2 += k0 * a.y + k1 * a.z + k2 * a.w;
            o3 += k0 * a.z + k1 * a.w + k2 * xq;
            p0 += m0 * xm  + m1 * a.x + m2 * a.y;
            p1 += m0 * a.x + m1 * a.y + m2 * a.z;
            p2 += m0 * a.y + m1 * a.z + m2 * a.w;
            p3 += m0 * a.z + m1 * a.w + m2 * xq;
        }
        ushort4 pk1 = { f2b(o0), f2b(o1), f2b(o2), f2b(o3) };
        *(ushort4*)(Xs + grp * 4) = pk1;
        ushort4 pk2 = { f2b(p0), f2b(p1), f2b(p2), f2b(p3) };
        *(ushort4*)(Vd + grp * 4) = pk2;
    }
}

// ---------------------------------------------------------------------------
// K4: fused sf GEMM + W1 GEMM + finish. Block = (b, h) (px chunk == row h).
//  Stage XV + Y2 (swizzled bf16, 48 KB) -> W1 GEMM (8 waves) + sf GEMM
//  (waves 4-7) -> W1/sf to LDS -> finish: out = W1 + sum_t sf[t]*U[shift_t].
// ---------------------------------------------------------------------------
__global__ __launch_bounds__(512, 2) void k_sfW1fin(
    const unsigned short* __restrict__ XV, const float* __restrict__ Y2,
    const unsigned short* __restrict__ wfb, const unsigned short* __restrict__ wsb,
    const unsigned short* __restrict__ U, float* __restrict__ out)
{
    __shared__ unsigned short sFt[Wn][256];   // 32 KB; reused as W1lds[128][64]
    __shared__ unsigned short sY[Wn][128];    // 16 KB; reused as sSf[9][64] f32

    int bid = blockIdx.x;
    int b = bid & 7, h = bid >> 3;
    int px0 = h * Wn;
    int t = threadIdx.x, pq = t & 15, c0 = t >> 4;   // c0 in [0,32)

#pragma unroll
    for (int i = 0; i < 8; i++) {
        int c = c0 + 32 * i;
        ushort4 v = *(const ushort4*)(XV + ((size_t)(b * 256 + c) * HWn + px0 + pq * 4));
        const unsigned short* va = (const unsigned short*)&v;
#pragma unroll
        for (int j = 0; j < 4; j++) {
            int px = pq * 4 + j;
            sFt[px][c ^ SWZ(px)] = va[j];
        }
    }
#pragma unroll
    for (int i = 0; i < 4; i++) {
        int c = c0 + 32 * i;
        float4 v = *(const float4*)(Y2 + ((size_t)(b * Cn + c) * HWn + px0 + pq * 4));
        float va[4] = { v.x, v.y, v.z, v.w };
#pragma unroll
        for (int j = 0; j < 4; j++) {
            int px = pq * 4 + j;
            sY[px][c ^ SWZ(px)] = f2b(va[j]);
        }
    }
    __syncthreads();

    int lane = t & 63, wv = t >> 6;
    int l16 = lane & 15, half = lane >> 4, kk = half * 8;

    // ---- W1 GEMM (all 8 waves): o0 = (wv&3)*32, pxh = (wv>>2)*32
    int o0 = (wv & 3) * 32, pxh = (wv >> 2) * 32;
    f32x4 acc[2][2];
#pragma unroll
    for (int m = 0; m < 2; m++)
#pragma unroll
        for (int n = 0; n < 2; n++)
            acc[m][n] = (f32x4){0.f, 0.f, 0.f, 0.f};
#pragma unroll
    for (int ks = 0; ks < 8; ks++) {
        short8 av[2];
#pragma unroll
        for (int m = 0; m < 2; m++)
            av[m] = *(const short8*)(wfb + (o0 + m * 16 + l16) * 256 + ks * 32 + kk);
#pragma unroll
        for (int n = 0; n < 2; n++) {
            int px = pxh + n * 16 + l16;
            int col = (ks * 32 + kk) ^ SWZ(px);
            short8 bv = *(const short8*)(&sFt[px][0] + col);
#pragma unroll
            for (int m = 0; m < 2; m++)
                acc[m][n] = __builtin_amdgcn_mfma_f32_16x16x32_bf16(av[m], bv, acc[m][n], 0, 0, 0);
        }
    }

    // ---- sf GEMM (waves 4..7): px 16-chunk each
    f32x4 accs = (f32x4){0.f, 0.f, 0.f, 0.f};
    int pxs = (wv - 4) * 16 + l16;
    if (wv >= 4) {
#pragma unroll
        for (int ks = 0; ks < 4; ks++) {
            short8 av = *(const short8*)(wsb + l16 * 256 + ks * 32 + kk);
            int col = (ks * 32 + kk) ^ SWZ(pxs);
            short8 bv = *(const short8*)(&sFt[pxs][0] + col);
            accs = __builtin_amdgcn_mfma_f32_16x16x32_bf16(av, bv, accs, 0, 0, 0);
        }
#pragma unroll
        for (int ks = 0; ks < 4; ks++) {
            short8 av = *(const short8*)(wsb + l16 * 256 + 128 + ks * 32 + kk);
            int col = (ks * 32 + kk) ^ SWZ(pxs);
            short8 bv = *(const short8*)(&sY[pxs][0] + col);
            accs = __builtin_amdgcn_mfma_f32_16x16x32_bf16(av, bv, accs, 0, 0, 0);
        }
    }
    __syncthreads();   // all LDS reads done; safe to overwrite

    // ---- stash W1 (bf16) and sf (f32) in LDS
    unsigned short* W1lds = &sFt[0][0];        // [128][64]
    float* sSf = (float*)&sY[0][0];            // [9][64]
#pragma unroll
    for (int m = 0; m < 2; m++)
#pragma unroll
        for (int n = 0; n < 2; n++)
#pragma unroll
            for (int r = 0; r < 4; r++) {
                int o = o0 + m * 16 + half * 4 + r;
                int px = pxh + n * 16 + l16;
                W1lds[o * 64 + px] = f2b(acc[m][n][r]);
            }
    if (wv >= 4) {
#pragma unroll
        for (int r = 0; r < 4; r++) {
            int tt = half * 4 + r;
            if (tt < KK) sSf[tt * 64 + pxs] = accs[r];
        }
    }
    __syncthreads();

    // ---- finish: out[o][w] = W1[o][w] + sum_t sf[t][w] * Upad[o][h+dh][w+dw]
    {
        int w = t & 63, og = t >> 6;
        bool hm = h > 0, hp = h < Hn - 1;
        float sfw[9];
#pragma unroll
        for (int q = 0; q < 9; q++) sfw[q] = sSf[q * 64 + w];

        size_t base = (size_t)(b * Cn + og * 16) * HWn + px0 + w;
#pragma unroll
        for (int i = 0; i < 16; i++) {
            const unsigned short* up = U + base + (size_t)i * HWn;
            float r0 = hm ? b2f(up[-Wn]) : 0.f;
            float r1 = b2f(up[0]);
            float r2 = hp ? b2f(up[Wn]) : 0.f;
            float xl0 = __shfl_up(r0, 1), xr0 = __shfl_down(r0, 1);
            float xl1 = __shfl_up(r1, 1), xr1 = __shfl_down(r1, 1);
            float xl2 = __shfl_up(r2, 1), xr2 = __shfl_down(r2, 1);
            if (w == 0)  { xl0 = 0.f; xl1 = 0.f; xl2 = 0.f; }
            if (w == 63) { xr0 = 0.f; xr1 = 0.f; xr2 = 0.f; }
            float a = sfw[0] * xl0 + sfw[1] * r0 + sfw[2] * xr0
                    + sfw[3] * xl1 + sfw[4] * r1 + sfw[5] * xr1
                    + sfw[6] * xl2 + sfw[7] * r2 + sfw[8] * xr2;
            int o = og * 16 + i;
            a += b2f(W1lds[o * 64 + w]);
            __builtin_nontemporal_store(a, &out[base + (size_t)i * HWn]);
        }
    }
}

// ---------------------------------------------------------------------------
extern "C" void kernel_launch(void* const* d_in, const int* in_sizes, int n_in,
                              void* d_out, int out_size, void* d_ws, size_t ws_size,
                              hipStream_t stream) {
    (void)in_sizes; (void)n_in; (void)out_size; (void)ws_size;
    const float* X2  = (const float*)d_in[0];
    const float* Y2  = (const float*)d_in[1];
    const float* sw  = (const float*)d_in[2];
    const float* w1  = (const float*)d_in[3];
    const float* w2  = (const float*)d_in[4];
    const float* w3  = (const float*)d_in[5];
    const float* wsp = (const float*)d_in[6];
    const float* wf  = (const float*)d_in[7];
    float* out = (float*)d_out;

    float* wsf = (float*)d_ws;
    unsigned short* XV = (unsigned short*)wsf;             // 16 MB
    unsigned short* U  = (unsigned short*)(wsf + 4194304); // 8 MB
    float* pws = wsf + 6291456;                            // 10240 f
    float* cfG = wsf + 6301696;                            // 9216 f
    unsigned short* wfb = (unsigned short*)(wsf + 6310912); // 32768 u16
    unsigned short* wsb = (unsigned short*)(wsf + 6327296); // 4096 u16

    hipLaunchKernelGGL(k_pre, dim3(Bn * Cn), dim3(256), 0, stream,
                       X2, Y2, wf, wsp, pws, wfb, wsb);
    hipLaunchKernelGGL(k_mlpU, dim3(520), dim3(256), 0, stream,
                       pws, sw, w1, w2, w3, X2, wfb, cfG, U);
    hipLaunchKernelGGL(k_conv, dim3(Bn * Cn), dim3(256), 0, stream,
                       X2, sw, cfG, XV);
    hipLaunchKernelGGL(k_sfW1fin, dim3(Bn * Hn), dim3(512), 0, stream,
                       XV, Y2, wfb, wsb, U, out);
}